// Round 1
// baseline (776.600 us; speedup 1.0000x reference)
//
#include <hip/hip_runtime.h>
#include <math.h>

// ---------- constants ----------
#define B_  2
#define T_  4096
#define DM  2048
#define H_  16
#define HKV 4
#define DS_ 32
#define DG_ 32
#define DV_ 64
#define DQK 64          // DS+DG concatenated
#define MB_ 64
#define LW_ 1024
#define REMOTE 3072     // T - LW
#define NBLK 48         // REMOTE/MB
#define KTOT 1072       // NBLK + LW
#define NTILES 17       // ceil(1072/64)

typedef __bf16 bf16x8 __attribute__((ext_vector_type(8)));
typedef float  f32x4  __attribute__((ext_vector_type(4)));

__device__ __forceinline__ float bf2f(unsigned short u) {
    unsigned int x = ((unsigned int)u) << 16;
    return __builtin_bit_cast(float, x);
}
__device__ __forceinline__ unsigned short f2bf(float f) {
    unsigned int x = __builtin_bit_cast(unsigned int, f);
    x = x + 0x7fffu + ((x >> 16) & 1u);   // round-to-nearest-even
    return (unsigned short)(x >> 16);
}

// ---------- fp32 -> bf16 bulk convert ----------
__global__ void cvt_f32_to_bf16(const float* __restrict__ src,
                                unsigned short* __restrict__ dst, int n) {
    int i = (blockIdx.x * blockDim.x + threadIdx.x) * 4;
    if (i >= n) return;
    float4 v = *(const float4*)(src + i);
    ushort4 o;
    o.x = f2bf(v.x); o.y = f2bf(v.y); o.z = f2bf(v.z); o.w = f2bf(v.w);
    *(ushort4*)(dst + i) = o;
}

// ---------- transpose + convert: src[R][C] f32 -> dst[C][R] bf16 ----------
__global__ void transpose_cvt(const float* __restrict__ src,
                              unsigned short* __restrict__ dst, int R, int C) {
    __shared__ float tile[32][33];
    int ct = blockIdx.x, rt = blockIdx.y;
    int tx = threadIdx.x, ty = threadIdx.y;
    #pragma unroll
    for (int i = ty; i < 32; i += 8)
        tile[i][tx] = src[(size_t)(rt * 32 + i) * C + ct * 32 + tx];
    __syncthreads();
    #pragma unroll
    for (int i = ty; i < 32; i += 8)
        dst[(size_t)(ct * 32 + i) * R + rt * 32 + tx] = f2bf(tile[tx][i]);
}

// ---------- bf16 MFMA GEMM, B pre-transposed: C[M,N] = A[M,K] * BT[N,K]^T ----
// 256 thr = 4 waves (2x2), each wave 64x64 out, 4x4 frags of 16x16, BK=32.
// MODE 0: scatter-epilogue into qcat/kcatf/vf (proj GEMM, N=1536)
// MODE 1: plain f32 store (Wo GEMM)
// ABL 0: A/B frag k = (lane>>4)*8 + e (contiguous-8).  (flip to 1 if wrong)
template<int MODE, int ABL>
__global__ __launch_bounds__(256) void gemm_bt(
    const unsigned short* __restrict__ A,
    const unsigned short* __restrict__ BT,
    float* __restrict__ outF,
    unsigned short* __restrict__ qcat,
    unsigned short* __restrict__ kcatf,
    unsigned short* __restrict__ vf,
    int M, int N, int K)
{
    __shared__ unsigned short As[128][40];
    __shared__ unsigned short Bs[128][40];
    const int tid  = threadIdx.x;
    const int lane = tid & 63, wave = tid >> 6;
    const int wr = wave >> 1, wc = wave & 1;
    const int row0 = blockIdx.y * 128, col0 = blockIdx.x * 128;
    const int lr = lane & 15;
    f32x4 acc[4][4] = {};

    for (int kk = 0; kk < K; kk += 32) {
        #pragma unroll
        for (int c = tid; c < 512; c += 256) {
            int r = c >> 2, p = (c & 3) * 8;
            *(uint4*)&As[r][p] = *(const uint4*)&A [(size_t)(row0 + r) * K + kk + p];
            *(uint4*)&Bs[r][p] = *(const uint4*)&BT[(size_t)(col0 + r) * K + kk + p];
        }
        __syncthreads();
        bf16x8 af[4], bfr[4];
        if (ABL == 0) {
            int lk = (lane >> 4) * 8;
            #pragma unroll
            for (int mf = 0; mf < 4; mf++)
                af[mf] = __builtin_bit_cast(bf16x8, *(const uint4*)&As[wr*64 + mf*16 + lr][lk]);
            #pragma unroll
            for (int nf = 0; nf < 4; nf++)
                bfr[nf] = __builtin_bit_cast(bf16x8, *(const uint4*)&Bs[wc*64 + nf*16 + lr][lk]);
        } else {
            // split layout: e<4 -> k=(l>>4)*4+e ; e>=4 -> k=16+(l>>4)*4+(e-4)
            int lk = (lane >> 4) * 4;
            #pragma unroll
            for (int mf = 0; mf < 4; mf++) {
                bf16x8 t;
                #pragma unroll
                for (int e = 0; e < 4; e++) {
                    t[e]   = __builtin_bit_cast(__bf16, As[wr*64 + mf*16 + lr][lk + e]);
                    t[e+4] = __builtin_bit_cast(__bf16, As[wr*64 + mf*16 + lr][16 + lk + e]);
                }
                af[mf] = t;
            }
            #pragma unroll
            for (int nf = 0; nf < 4; nf++) {
                bf16x8 t;
                #pragma unroll
                for (int e = 0; e < 4; e++) {
                    t[e]   = __builtin_bit_cast(__bf16, Bs[wc*64 + nf*16 + lr][lk + e]);
                    t[e+4] = __builtin_bit_cast(__bf16, Bs[wc*64 + nf*16 + lr][16 + lk + e]);
                }
                bfr[nf] = t;
            }
        }
        #pragma unroll
        for (int mf = 0; mf < 4; mf++)
            #pragma unroll
            for (int nf = 0; nf < 4; nf++)
                acc[mf][nf] = __builtin_amdgcn_mfma_f32_16x16x32_bf16(
                                  af[mf], bfr[nf], acc[mf][nf], 0, 0, 0);
        __syncthreads();
    }

    const int r0 = (lane >> 4) * 4, c0 = lane & 15;
    #pragma unroll
    for (int mf = 0; mf < 4; mf++) {
        #pragma unroll
        for (int nf = 0; nf < 4; nf++) {
            #pragma unroll
            for (int r = 0; r < 4; r++) {
                int row = row0 + wr*64 + mf*16 + r0 + r;
                int col = col0 + wc*64 + nf*16 + c0;
                float v = acc[mf][nf][r];
                if (MODE == 1) {
                    outF[(size_t)row * N + col] = v;
                } else {
                    int b = row >> 12, t = row & 4095;
                    unsigned short hv = f2bf(v);
                    if (col < 512) {                       // q_sem
                        int h = col >> 5, d = col & 31;
                        qcat[(((size_t)(b*16 + h))*4096 + t)*64 + d] = hv;
                    } else if (col < 1024) {               // q_geo
                        int c2 = col - 512; int h = c2 >> 5, d = c2 & 31;
                        qcat[(((size_t)(b*16 + h))*4096 + t)*64 + 32 + d] = hv;
                    } else if (col < 1152) {               // k_sem
                        int c2 = col - 1024; int g = c2 >> 5, d = c2 & 31;
                        kcatf[(((size_t)(b*4 + g))*4096 + t)*64 + d] = hv;
                    } else if (col < 1280) {               // k_geo
                        int c2 = col - 1152; int g = c2 >> 5, d = c2 & 31;
                        kcatf[(((size_t)(b*4 + g))*4096 + t)*64 + 32 + d] = hv;
                    } else {                               // v
                        int c2 = col - 1280; int g = c2 >> 6, d = c2 & 63;
                        vf[(((size_t)(b*4 + g))*4096 + t)*64 + d] = hv;
                    }
                }
            }
        }
    }
}

// ---------- RoPE rotate (in-place, dims 32..63 of each 64-dim row) ----------
__global__ void rope_rotate(unsigned short* __restrict__ buf, int nrows, int T) {
    int idx = blockIdx.x * 256 + threadIdx.x;
    int row = idx >> 4, i = idx & 15;
    if (row >= nrows) return;
    int t = row % T;
    float inv = exp2f(-(float)i * 0.8304820237218406f);   // 10000^(-i/16)
    float ang = (float)t * inv;
    float s, c;
    sincosf(ang, &s, &c);
    unsigned short* p = buf + (size_t)row * 64;
    float g1 = bf2f(p[32 + i]), g2 = bf2f(p[48 + i]);
    p[32 + i] = f2bf(g1 * c - g2 * s);
    p[48 + i] = f2bf(g2 * c + g1 * s);
}

// ---------- mem-block pooling: full-res KV -> 1072 summarized keys ----------
__global__ void pool_kv(const unsigned short* __restrict__ kf,
                        const unsigned short* __restrict__ vfull,
                        unsigned short* __restrict__ kp,
                        unsigned short* __restrict__ vp) {
    int key = blockIdx.x % KTOT;
    int bg  = blockIdx.x / KTOT;
    int d = threadIdx.x;
    size_t srcbase = (size_t)bg * T_ * 64;
    size_t dst = ((size_t)bg * KTOT + key) * 64 + d;
    if (key < NBLK) {
        float sk = 0.f, sv = 0.f;
        for (int j = 0; j < MB_; j++) {
            size_t o = srcbase + (size_t)(key * MB_ + j) * 64 + d;
            sk += bf2f(kf[o]);
            sv += bf2f(vfull[o]);
        }
        kp[dst] = f2bf(sk * (1.f / 64.f));
        vp[dst] = f2bf(sv * (1.f / 64.f));
    } else {
        int t = REMOTE + key - NBLK;
        size_t o = srcbase + (size_t)t * 64 + d;
        kp[dst] = kf[o];
        vp[dst] = vfull[o];
    }
}

// ---------- flash attention over summarized keys (fp32 math) ----------
// grid (qt=64, h=16, b=2), 256 thr (16x16, each 4x4 micro-tile of 64x64).
__global__ __launch_bounds__(256) void attn_fwd(
    const unsigned short* __restrict__ qcat,
    const unsigned short* __restrict__ kp,
    const unsigned short* __restrict__ vp,
    const float* __restrict__ ls,
    unsigned short* __restrict__ attn_out)
{
    __shared__ float Qs[64][67];
    __shared__ float KS[64][67];   // K tile, reused for P tile
    __shared__ float Vs[64][67];
    __shared__ float rowScale[64], rowL[64];

    const int qt = blockIdx.x, h = blockIdx.y, b = blockIdx.z;
    const int g = h >> 2;
    const int q0 = qt * 64;
    const int tid = threadIdx.x;
    const int tx = tid & 15, ty = tid >> 4;
    const float sc = expf(ls[h]) * 0.17677669529663687f;   // exp(ls)/sqrt(32)

    const unsigned short* qbase = qcat + (((size_t)(b * 16 + h)) * T_ + q0) * 64;
    for (int e = tid; e < 1024; e += 256) {
        int r = e >> 4, c4 = (e & 15) * 4;
        ushort4 u = *(const ushort4*)(qbase + r * 64 + c4);
        Qs[r][c4 + 0] = bf2f(u.x) * sc;
        Qs[r][c4 + 1] = bf2f(u.y) * sc;
        Qs[r][c4 + 2] = bf2f(u.z) * sc;
        Qs[r][c4 + 3] = bf2f(u.w) * sc;
    }

    float m = -1e9f, l = 0.f;        // valid in threads tid<64 (row owner)
    float acc[4][4] = {};
    const size_t kvbase = ((size_t)(b * 4 + g)) * KTOT * 64;

    for (int kt = 0; kt < NTILES; kt++) {
        // tiles kt>=1 hold only local keys with min pos 3024+kt*64 (increasing)
        if (q0 != 0 && kt > 0 && (3024 + kt * 64) > (q0 + 63)) break;
        int kb = kt * 64;
        for (int e = tid; e < 1024; e += 256) {
            int r = e >> 4, c4 = (e & 15) * 4;
            int key = kb + r;
            if (key < KTOT) {
                ushort4 ku = *(const ushort4*)(kp + kvbase + (size_t)key * 64 + c4);
                ushort4 vu = *(const ushort4*)(vp + kvbase + (size_t)key * 64 + c4);
                KS[r][c4+0] = bf2f(ku.x); KS[r][c4+1] = bf2f(ku.y);
                KS[r][c4+2] = bf2f(ku.z); KS[r][c4+3] = bf2f(ku.w);
                Vs[r][c4+0] = bf2f(vu.x); Vs[r][c4+1] = bf2f(vu.y);
                Vs[r][c4+2] = bf2f(vu.z); Vs[r][c4+3] = bf2f(vu.w);
            } else {
                KS[r][c4+0] = 0.f; KS[r][c4+1] = 0.f; KS[r][c4+2] = 0.f; KS[r][c4+3] = 0.f;
                Vs[r][c4+0] = 0.f; Vs[r][c4+1] = 0.f; Vs[r][c4+2] = 0.f; Vs[r][c4+3] = 0.f;
            }
        }
        __syncthreads();

        // S = Q K^T (4x4 per thread)
        float s[4][4] = {};
        for (int d = 0; d < 64; d++) {
            float qv[4], kv[4];
            #pragma unroll
            for (int i = 0; i < 4; i++) qv[i] = Qs[ty * 4 + i][d];
            #pragma unroll
            for (int j = 0; j < 4; j++) kv[j] = KS[tx * 4 + j][d];
            #pragma unroll
            for (int i = 0; i < 4; i++)
                #pragma unroll
                for (int j = 0; j < 4; j++)
                    s[i][j] += qv[i] * kv[j];
        }
        __syncthreads();   // all KS reads done -> safe to overwrite with P

        #pragma unroll
        for (int i = 0; i < 4; i++) {
            int qpos = q0 + ty * 4 + i;
            #pragma unroll
            for (int j = 0; j < 4; j++) {
                int key = kb + tx * 4 + j;
                float val;
                if (key >= KTOT) val = -INFINITY;           // pad keys: exact 0 prob
                else {
                    int kpos = (key < NBLK) ? key * 64 + 63 : 3024 + key;
                    val = (kpos <= qpos) ? s[i][j] : -1e9f; // matches reference NEG_INF
                }
                KS[ty * 4 + i][tx * 4 + j] = val;
            }
        }
        __syncthreads();

        // online softmax, one thread per row
        if (tid < 64) {
            float tmax = -INFINITY;
            for (int c2 = 0; c2 < 64; c2++) tmax = fmaxf(tmax, KS[tid][c2]);
            float mn = fmaxf(m, tmax);
            float scl = expf(m - mn);
            float lsum = 0.f;
            for (int c2 = 0; c2 < 64; c2++) {
                float pexp = expf(KS[tid][c2] - mn);
                KS[tid][c2] = pexp;
                lsum += pexp;
            }
            l = l * scl + lsum;
            m = mn;
            rowScale[tid] = scl;
        }
        __syncthreads();

        // PV accumulate
        #pragma unroll
        for (int i = 0; i < 4; i++) {
            float scl = rowScale[ty * 4 + i];
            #pragma unroll
            for (int j = 0; j < 4; j++) acc[i][j] *= scl;
        }
        for (int k2 = 0; k2 < 64; k2++) {
            float pv[4], vv[4];
            #pragma unroll
            for (int i = 0; i < 4; i++) pv[i] = KS[ty * 4 + i][k2];
            #pragma unroll
            for (int j = 0; j < 4; j++) vv[j] = Vs[k2][tx * 4 + j];
            #pragma unroll
            for (int i = 0; i < 4; i++)
                #pragma unroll
                for (int j = 0; j < 4; j++)
                    acc[i][j] += pv[i] * vv[j];
        }
        __syncthreads();   // protect KS/Vs before next tile staging
    }

    if (tid < 64) rowL[tid] = l;
    __syncthreads();
    #pragma unroll
    for (int i = 0; i < 4; i++) {
        int qi = ty * 4 + i;
        float inv = 1.f / rowL[qi];
        ushort4 o;
        o.x = f2bf(acc[i][0] * inv);
        o.y = f2bf(acc[i][1] * inv);
        o.z = f2bf(acc[i][2] * inv);
        o.w = f2bf(acc[i][3] * inv);
        *(ushort4*)(attn_out + ((size_t)(b * T_ + q0 + qi)) * 1024 + h * 64 + tx * 4) = o;
    }
}

// ---------- host launch ----------
extern "C" void kernel_launch(void* const* d_in, const int* in_sizes, int n_in,
                              void* d_out, int out_size, void* d_ws, size_t ws_size,
                              hipStream_t stream) {
    const float* x      = (const float*)d_in[0];
    const float* Wq_sem = (const float*)d_in[1];
    const float* Wk_sem = (const float*)d_in[2];
    const float* Wq_geo = (const float*)d_in[3];
    const float* Wk_geo = (const float*)d_in[4];
    const float* Wv     = (const float*)d_in[5];
    const float* Wo     = (const float*)d_in[6];
    const float* ls     = (const float*)d_in[7];

    char* w = (char*)d_ws;
    auto alloc = [&](size_t bytes) {
        char* p = w;
        w += (bytes + 255) & ~(size_t)255;
        return p;
    };
    unsigned short* xb    = (unsigned short*)alloc((size_t)8192 * 2048 * 2);
    unsigned short* WcatT = (unsigned short*)alloc((size_t)1536 * 2048 * 2);
    unsigned short* WoT   = (unsigned short*)alloc((size_t)2048 * 1024 * 2);
    unsigned short* qcat  = (unsigned short*)alloc((size_t)2 * 16 * 4096 * 64 * 2);
    unsigned short* kcatf = (unsigned short*)alloc((size_t)2 * 4 * 4096 * 64 * 2);
    unsigned short* vfull = (unsigned short*)alloc((size_t)2 * 4 * 4096 * 64 * 2);
    unsigned short* kcatp = (unsigned short*)alloc((size_t)2 * 4 * 1072 * 64 * 2);
    unsigned short* vpool = (unsigned short*)alloc((size_t)2 * 4 * 1072 * 64 * 2);
    unsigned short* aout  = (unsigned short*)alloc((size_t)8192 * 1024 * 2);

    // 1) x -> bf16
    cvt_f32_to_bf16<<<16384, 256, 0, stream>>>(x, xb, 8192 * 2048);

    // 2) weights -> bf16, transposed to [N][K]
    dim3 tb(32, 8);
    transpose_cvt<<<dim3(16, 64), tb, 0, stream>>>(Wq_sem, WcatT + (size_t)0    * 2048, 2048, 512);
    transpose_cvt<<<dim3(16, 64), tb, 0, stream>>>(Wq_geo, WcatT + (size_t)512  * 2048, 2048, 512);
    transpose_cvt<<<dim3( 4, 64), tb, 0, stream>>>(Wk_sem, WcatT + (size_t)1024 * 2048, 2048, 128);
    transpose_cvt<<<dim3( 4, 64), tb, 0, stream>>>(Wk_geo, WcatT + (size_t)1152 * 2048, 2048, 128);
    transpose_cvt<<<dim3( 8, 64), tb, 0, stream>>>(Wv,     WcatT + (size_t)1280 * 2048, 2048, 256);
    transpose_cvt<<<dim3(64, 32), tb, 0, stream>>>(Wo, WoT, 1024, 2048);

    // 3) fused projection GEMM -> qcat / kcatf / vfull (bf16)
    gemm_bt<0, 0><<<dim3(12, 64), 256, 0, stream>>>(
        xb, WcatT, nullptr, qcat, kcatf, vfull, 8192, 1536, 2048);

    // 4) RoPE on geo halves
    rope_rotate<<<8192, 256, 0, stream>>>(qcat, 2 * 16 * 4096, 4096);
    rope_rotate<<<2048, 256, 0, stream>>>(kcatf, 2 * 4 * 4096, 4096);

    // 5) memory-block pooling
    pool_kv<<<8 * KTOT, 64, 0, stream>>>(kcatf, vfull, kcatp, vpool);

    // 6) flash attention over 1072 summarized keys
    attn_fwd<<<dim3(64, 16, 2), 256, 0, stream>>>(qcat, kcatp, vpool, ls, aout);

    // 7) output projection -> d_out (fp32)
    gemm_bt<1, 0><<<dim3(16, 64), 256, 0, stream>>>(
        aout, WoT, (float*)d_out, nullptr, nullptr, nullptr, 8192, 2048, 1024);
}

// Round 3
// 386.183 us; speedup vs baseline: 2.0110x; 2.0110x over previous
//
#include <hip/hip_runtime.h>
#include <math.h>

// ---------- constants ----------
#define B_  2
#define T_  4096
#define DM  2048
#define H_  16
#define HKV 4
#define DV_ 64
#define DQK 64          // DS+DG concatenated
#define MB_ 64
#define LW_ 1024
#define REMOTE 3072     // T - LW
#define NBLK 48         // REMOTE/MB
#define KTOT 1072       // NBLK + LW
#define NTILES 17       // ceil(1072/64)
#define QBLK 128

typedef __bf16 bf16x8 __attribute__((ext_vector_type(8)));
typedef float  f32x4  __attribute__((ext_vector_type(4)));

__device__ __forceinline__ float bf2f(unsigned short u) {
    unsigned int x = ((unsigned int)u) << 16;
    return __builtin_bit_cast(float, x);
}
__device__ __forceinline__ unsigned short f2bf(float f) {
    unsigned int x = __builtin_bit_cast(unsigned int, f);
    x = x + 0x7fffu + ((x >> 16) & 1u);   // round-to-nearest-even
    return (unsigned short)(x >> 16);
}

// ---------- fp32 -> bf16 bulk convert ----------
__global__ void cvt_f32_to_bf16(const float* __restrict__ src,
                                unsigned short* __restrict__ dst, int n) {
    int i = (blockIdx.x * blockDim.x + threadIdx.x) * 4;
    if (i >= n) return;
    float4 v = *(const float4*)(src + i);
    ushort4 o;
    o.x = f2bf(v.x); o.y = f2bf(v.y); o.z = f2bf(v.z); o.w = f2bf(v.w);
    *(ushort4*)(dst + i) = o;
}

// ---------- transpose + convert: src[R][C] f32 -> dst[C][R] bf16 ----------
__global__ void transpose_cvt(const float* __restrict__ src,
                              unsigned short* __restrict__ dst, int R, int C) {
    __shared__ float tile[32][33];
    int ct = blockIdx.x, rt = blockIdx.y;
    int tx = threadIdx.x, ty = threadIdx.y;
    #pragma unroll
    for (int i = ty; i < 32; i += 8)
        tile[i][tx] = src[(size_t)(rt * 32 + i) * C + ct * 32 + tx];
    __syncthreads();
    #pragma unroll
    for (int i = ty; i < 32; i += 8)
        dst[(size_t)(ct * 32 + i) * R + rt * 32 + tx] = f2bf(tile[tx][i]);
}

// ---------- bf16 MFMA GEMM, B pre-transposed: C[M,N] = A[M,K] * BT[N,K]^T ----
// MODE 0: scatter-epilogue into qcat/kcatf/vf (proj GEMM, N=1536)
// MODE 1: plain f32 store (Wo GEMM)
template<int MODE>
__global__ __launch_bounds__(256) void gemm_bt(
    const unsigned short* __restrict__ A,
    const unsigned short* __restrict__ BT,
    float* __restrict__ outF,
    unsigned short* __restrict__ qcat,
    unsigned short* __restrict__ kcatf,
    unsigned short* __restrict__ vf,
    int M, int N, int K)
{
    __shared__ unsigned short As[128][40];
    __shared__ unsigned short Bs[128][40];
    const int tid  = threadIdx.x;
    const int lane = tid & 63, wave = tid >> 6;
    const int wr = wave >> 1, wc = wave & 1;
    const int row0 = blockIdx.y * 128, col0 = blockIdx.x * 128;
    const int lr = lane & 15;
    f32x4 acc[4][4] = {};

    for (int kk = 0; kk < K; kk += 32) {
        #pragma unroll
        for (int c = tid; c < 512; c += 256) {
            int r = c >> 2, p = (c & 3) * 8;
            *(uint4*)&As[r][p] = *(const uint4*)&A [(size_t)(row0 + r) * K + kk + p];
            *(uint4*)&Bs[r][p] = *(const uint4*)&BT[(size_t)(col0 + r) * K + kk + p];
        }
        __syncthreads();
        bf16x8 af[4], bfr[4];
        int lk = (lane >> 4) * 8;
        #pragma unroll
        for (int mf = 0; mf < 4; mf++)
            af[mf] = __builtin_bit_cast(bf16x8, *(const uint4*)&As[wr*64 + mf*16 + lr][lk]);
        #pragma unroll
        for (int nf = 0; nf < 4; nf++)
            bfr[nf] = __builtin_bit_cast(bf16x8, *(const uint4*)&Bs[wc*64 + nf*16 + lr][lk]);
        #pragma unroll
        for (int mf = 0; mf < 4; mf++)
            #pragma unroll
            for (int nf = 0; nf < 4; nf++)
                acc[mf][nf] = __builtin_amdgcn_mfma_f32_16x16x32_bf16(
                                  af[mf], bfr[nf], acc[mf][nf], 0, 0, 0);
        __syncthreads();
    }

    const int r0 = (lane >> 4) * 4, c0 = lane & 15;
    #pragma unroll
    for (int mf = 0; mf < 4; mf++) {
        #pragma unroll
        for (int nf = 0; nf < 4; nf++) {
            #pragma unroll
            for (int r = 0; r < 4; r++) {
                int row = row0 + wr*64 + mf*16 + r0 + r;
                int col = col0 + wc*64 + nf*16 + c0;
                float v = acc[mf][nf][r];
                if (MODE == 1) {
                    outF[(size_t)row * N + col] = v;
                } else {
                    int b = row >> 12, t = row & 4095;
                    unsigned short hv = f2bf(v);
                    if (col < 512) {                       // q_sem
                        int h = col >> 5, d = col & 31;
                        qcat[(((size_t)(b*16 + h))*4096 + t)*64 + d] = hv;
                    } else if (col < 1024) {               // q_geo
                        int c2 = col - 512; int h = c2 >> 5, d = c2 & 31;
                        qcat[(((size_t)(b*16 + h))*4096 + t)*64 + 32 + d] = hv;
                    } else if (col < 1152) {               // k_sem
                        int c2 = col - 1024; int g = c2 >> 5, d = c2 & 31;
                        kcatf[(((size_t)(b*4 + g))*4096 + t)*64 + d] = hv;
                    } else if (col < 1280) {               // k_geo
                        int c2 = col - 1152; int g = c2 >> 5, d = c2 & 31;
                        kcatf[(((size_t)(b*4 + g))*4096 + t)*64 + 32 + d] = hv;
                    } else {                               // v
                        int c2 = col - 1280; int g = c2 >> 6, d = c2 & 63;
                        vf[(((size_t)(b*4 + g))*4096 + t)*64 + d] = hv;
                    }
                }
            }
        }
    }
}

// ---------- RoPE rotate (in-place, dims 32..63 of each 64-dim row) ----------
__global__ void rope_rotate(unsigned short* __restrict__ buf, int nrows, int T) {
    int idx = blockIdx.x * 256 + threadIdx.x;
    int row = idx >> 4, i = idx & 15;
    if (row >= nrows) return;
    int t = row % T;
    float inv = exp2f(-(float)i * 0.8304820237218406f);   // 10000^(-i/16)
    float ang = (float)t * inv;
    float s, c;
    sincosf(ang, &s, &c);
    unsigned short* p = buf + (size_t)row * 64;
    float g1 = bf2f(p[32 + i]), g2 = bf2f(p[48 + i]);
    p[32 + i] = f2bf(g1 * c - g2 * s);
    p[48 + i] = f2bf(g2 * c + g1 * s);
}

// ---------- mem-block pooling: full-res KV -> 1072 summarized keys ----------
__global__ void pool_kv(const unsigned short* __restrict__ kf,
                        const unsigned short* __restrict__ vfull,
                        unsigned short* __restrict__ kp,
                        unsigned short* __restrict__ vp) {
    int key = blockIdx.x % KTOT;
    int bg  = blockIdx.x / KTOT;
    int d = threadIdx.x;
    size_t srcbase = (size_t)bg * T_ * 64;
    size_t dst = ((size_t)bg * KTOT + key) * 64 + d;
    if (key < NBLK) {
        float sk = 0.f, sv = 0.f;
        for (int j = 0; j < MB_; j++) {
            size_t o = srcbase + (size_t)(key * MB_ + j) * 64 + d;
            sk += bf2f(kf[o]);
            sv += bf2f(vfull[o]);
        }
        kp[dst] = f2bf(sk * (1.f / 64.f));
        vp[dst] = f2bf(sv * (1.f / 64.f));
    } else {
        int t = REMOTE + key - NBLK;
        size_t o = srcbase + (size_t)t * 64 + d;
        kp[dst] = kf[o];
        vp[dst] = vfull[o];
    }
}

// ---------- MFMA flash attention over 1072 summarized keys ----------
// grid (32 qblocks, 16 h, 2 b), 256 thr = 4 waves; wave w owns 32 queries.
// Per k-tile (64 keys): QK^T via 16 MFMA, wave-parallel online softmax,
// P->LDS(bf16), PV via 16 MFMA. K row-major LDS, V transposed LDS.
__global__ __launch_bounds__(256) void attn_fwd(
    const unsigned short* __restrict__ qcat,
    const unsigned short* __restrict__ kp,
    const unsigned short* __restrict__ vp,
    const float* __restrict__ ls,
    unsigned short* __restrict__ attn_out)
{
    __shared__ unsigned short Kl[64][72];    // [key][d]   pad->144B rows: 2-way free
    __shared__ unsigned short Vt[64][72];    // [v][key]   transposed
    __shared__ unsigned short Pl[128][72];   // [q][key]   bf16 P, wave-private rows

    const int qblk = 31 - blockIdx.x;        // heavy blocks first
    const int h = blockIdx.y, b = blockIdx.z, g = h >> 2;
    const int q0 = qblk * QBLK;
    const int tid = threadIdx.x;
    const int lane = tid & 63, w = tid >> 6;
    const int l15 = lane & 15, lg = lane >> 4;
    const float sc = __expf(ls[h]) * 0.17677669529663687f;   // exp(ls)/sqrt(32)

    // Q A-fragments in registers: aq[rowfrag][khalf]
    bf16x8 aq[2][2];
    const unsigned short* qbase =
        qcat + (((size_t)(b * 16 + h)) * T_ + q0 + w * 32) * 64;
    #pragma unroll
    for (int rf = 0; rf < 2; rf++)
        #pragma unroll
        for (int kh = 0; kh < 2; kh++)
            aq[rf][kh] = __builtin_bit_cast(bf16x8,
                *(const uint4*)(qbase + (size_t)(rf*16 + l15)*64 + kh*32 + lg*8));

    float m[2][4], lrun[2][4];
    #pragma unroll
    for (int rf = 0; rf < 2; rf++)
        #pragma unroll
        for (int r = 0; r < 4; r++) { m[rf][r] = -1e9f; lrun[rf][r] = 0.f; }
    f32x4 oacc[2][4] = {};

    const size_t kvbase = ((size_t)(b * 4 + g)) * KTOT * 64;
    const uint4 zero4 = {0, 0, 0, 0};

    for (int kt = 0; kt < NTILES; kt++) {
        // tiles kt>=1 hold only local keys; min pos 3024+kt*64 increases with kt
        if (kt > 0 && q0 != 0 && (3024 + kt * 64) > (q0 + QBLK - 1)) break;
        const int kb = kt * 64;

        // ---- stage K row-major (uint4 coalesced) ----
        #pragma unroll
        for (int i = tid; i < 512; i += 256) {
            int r = i >> 3, c8 = (i & 7) * 8;
            uint4 val = (kb + r < KTOT)
                ? *(const uint4*)(kp + kvbase + (size_t)(kb + r) * 64 + c8)
                : zero4;
            *(uint4*)&Kl[r][c8] = val;
        }
        // ---- stage V transposed: lane-pattern keeps writes conflict-free ----
        #pragma unroll
        for (int i = tid; i < 1024; i += 256) {
            int key = i & 63, c4 = (i >> 6) * 4;
            ushort4 vv;
            if (kb + key < KTOT)
                vv = *(const ushort4*)(vp + kvbase + (size_t)(kb + key) * 64 + c4);
            else
                vv = make_ushort4(0, 0, 0, 0);
            Vt[c4 + 0][key] = vv.x;
            Vt[c4 + 1][key] = vv.y;
            Vt[c4 + 2][key] = vv.z;
            Vt[c4 + 3][key] = vv.w;
        }
        __syncthreads();

        // ---- QK^T: S[32q][64k] per wave ----
        bf16x8 bk[4][2];
        #pragma unroll
        for (int nf = 0; nf < 4; nf++)
            #pragma unroll
            for (int kh = 0; kh < 2; kh++)
                bk[nf][kh] = __builtin_bit_cast(bf16x8,
                    *(const uint4*)&Kl[nf*16 + l15][kh*32 + lg*8]);
        f32x4 s[2][4] = {};
        #pragma unroll
        for (int rf = 0; rf < 2; rf++)
            #pragma unroll
            for (int nf = 0; nf < 4; nf++)
                #pragma unroll
                for (int kh = 0; kh < 2; kh++)
                    s[rf][nf] = __builtin_amdgcn_mfma_f32_16x16x32_bf16(
                                    aq[rf][kh], bk[nf][kh], s[rf][nf], 0, 0, 0);

        // ---- mask + wave-parallel online softmax + P->LDS ----
        #pragma unroll
        for (int rf = 0; rf < 2; rf++) {
            #pragma unroll
            for (int r = 0; r < 4; r++) {
                const int qpos = q0 + w*32 + rf*16 + lg*4 + r;
                float vals[4];
                float tmax = -INFINITY;
                #pragma unroll
                for (int nf = 0; nf < 4; nf++) {
                    int key = kb + nf*16 + l15;
                    float v = s[rf][nf][r] * sc;
                    int kpos = (key < NBLK) ? key * 64 + 63 : 3024 + key;
                    v = (key < KTOT) ? ((kpos <= qpos) ? v : -1e9f) : -INFINITY;
                    vals[nf] = v;
                    tmax = fmaxf(tmax, v);
                }
                #pragma unroll
                for (int d = 1; d < 16; d <<= 1)
                    tmax = fmaxf(tmax, __shfl_xor(tmax, d));
                float mn = fmaxf(m[rf][r], tmax);
                float scl = __expf(m[rf][r] - mn);
                m[rf][r] = mn;
                float rs = 0.f;
                #pragma unroll
                for (int nf = 0; nf < 4; nf++) {
                    unsigned short pb = f2bf(__expf(vals[nf] - mn));
                    rs += bf2f(pb);          // sum the ROUNDED p: exact convex comb
                    Pl[w*32 + rf*16 + lg*4 + r][nf*16 + l15] = pb;
                }
                #pragma unroll
                for (int d = 1; d < 16; d <<= 1)
                    rs += __shfl_xor(rs, d);
                lrun[rf][r] = lrun[rf][r] * scl + rs;
                #pragma unroll
                for (int nfv = 0; nfv < 4; nfv++)
                    oacc[rf][nfv][r] *= scl;
            }
        }

        // ---- PV: O += P V  (Pl rows are wave-private; no barrier needed) ----
        bf16x8 bv[4][2];
        #pragma unroll
        for (int nfv = 0; nfv < 4; nfv++)
            #pragma unroll
            for (int kh = 0; kh < 2; kh++)
                bv[nfv][kh] = __builtin_bit_cast(bf16x8,
                    *(const uint4*)&Vt[nfv*16 + l15][kh*32 + lg*8]);
        #pragma unroll
        for (int rf = 0; rf < 2; rf++) {
            bf16x8 pa[2];
            #pragma unroll
            for (int kh = 0; kh < 2; kh++)
                pa[kh] = __builtin_bit_cast(bf16x8,
                    *(const uint4*)&Pl[w*32 + rf*16 + l15][kh*32 + lg*8]);
            #pragma unroll
            for (int nfv = 0; nfv < 4; nfv++)
                #pragma unroll
                for (int kh = 0; kh < 2; kh++)
                    oacc[rf][nfv] = __builtin_amdgcn_mfma_f32_16x16x32_bf16(
                                        pa[kh], bv[nfv][kh], oacc[rf][nfv], 0, 0, 0);
        }

        __syncthreads();   // protect Kl/Vt before next tile's staging
    }

    // ---- epilogue: normalize and store ----
    #pragma unroll
    for (int rf = 0; rf < 2; rf++) {
        #pragma unroll
        for (int r = 0; r < 4; r++) {
            float inv = 1.f / lrun[rf][r];
            int q = q0 + w*32 + rf*16 + lg*4 + r;
            size_t obase = ((size_t)(b * T_ + q)) * 1024 + h * 64;
            #pragma unroll
            for (int nfv = 0; nfv < 4; nfv++)
                attn_out[obase + nfv*16 + l15] = f2bf(oacc[rf][nfv][r] * inv);
        }
    }
}

// ---------- host launch ----------
extern "C" void kernel_launch(void* const* d_in, const int* in_sizes, int n_in,
                              void* d_out, int out_size, void* d_ws, size_t ws_size,
                              hipStream_t stream) {
    const float* x      = (const float*)d_in[0];
    const float* Wq_sem = (const float*)d_in[1];
    const float* Wk_sem = (const float*)d_in[2];
    const float* Wq_geo = (const float*)d_in[3];
    const float* Wk_geo = (const float*)d_in[4];
    const float* Wv     = (const float*)d_in[5];
    const float* Wo     = (const float*)d_in[6];
    const float* ls     = (const float*)d_in[7];

    char* w = (char*)d_ws;
    auto alloc = [&](size_t bytes) {
        char* p = w;
        w += (bytes + 255) & ~(size_t)255;
        return p;
    };
    unsigned short* xb    = (unsigned short*)alloc((size_t)8192 * 2048 * 2);
    unsigned short* WcatT = (unsigned short*)alloc((size_t)1536 * 2048 * 2);
    unsigned short* WoT   = (unsigned short*)alloc((size_t)2048 * 1024 * 2);
    unsigned short* qcat  = (unsigned short*)alloc((size_t)2 * 16 * 4096 * 64 * 2);
    unsigned short* kcatf = (unsigned short*)alloc((size_t)2 * 4 * 4096 * 64 * 2);
    unsigned short* vfull = (unsigned short*)alloc((size_t)2 * 4 * 4096 * 64 * 2);
    unsigned short* kcatp = (unsigned short*)alloc((size_t)2 * 4 * 1072 * 64 * 2);
    unsigned short* vpool = (unsigned short*)alloc((size_t)2 * 4 * 1072 * 64 * 2);
    unsigned short* aout  = (unsigned short*)alloc((size_t)8192 * 1024 * 2);

    // 1) x -> bf16
    cvt_f32_to_bf16<<<16384, 256, 0, stream>>>(x, xb, 8192 * 2048);

    // 2) weights -> bf16, transposed to [N][K]
    dim3 tb(32, 8);
    transpose_cvt<<<dim3(16, 64), tb, 0, stream>>>(Wq_sem, WcatT + (size_t)0    * 2048, 2048, 512);
    transpose_cvt<<<dim3(16, 64), tb, 0, stream>>>(Wq_geo, WcatT + (size_t)512  * 2048, 2048, 512);
    transpose_cvt<<<dim3( 4, 64), tb, 0, stream>>>(Wk_sem, WcatT + (size_t)1024 * 2048, 2048, 128);
    transpose_cvt<<<dim3( 4, 64), tb, 0, stream>>>(Wk_geo, WcatT + (size_t)1152 * 2048, 2048, 128);
    transpose_cvt<<<dim3( 8, 64), tb, 0, stream>>>(Wv,     WcatT + (size_t)1280 * 2048, 2048, 256);
    transpose_cvt<<<dim3(64, 32), tb, 0, stream>>>(Wo, WoT, 1024, 2048);

    // 3) fused projection GEMM -> qcat / kcatf / vfull (bf16)
    gemm_bt<0><<<dim3(12, 64), 256, 0, stream>>>(
        xb, WcatT, nullptr, qcat, kcatf, vfull, 8192, 1536, 2048);

    // 4) RoPE on geo halves
    rope_rotate<<<8192, 256, 0, stream>>>(qcat, 2 * 16 * 4096, 4096);
    rope_rotate<<<2048, 256, 0, stream>>>(kcatf, 2 * 4 * 4096, 4096);

    // 5) memory-block pooling
    pool_kv<<<8 * KTOT, 64, 0, stream>>>(kcatf, vfull, kcatp, vpool);

    // 6) MFMA flash attention over 1072 summarized keys
    attn_fwd<<<dim3(32, 16, 2), 256, 0, stream>>>(qcat, kcatp, vpool, ls, aout);

    // 7) output projection -> d_out (fp32)
    gemm_bt<1><<<dim3(16, 64), 256, 0, stream>>>(
        aout, WoT, (float*)d_out, nullptr, nullptr, nullptr, 8192, 2048, 1024);
}

// Round 4
// 287.101 us; speedup vs baseline: 2.7050x; 1.3451x over previous
//
#include <hip/hip_runtime.h>
#include <math.h>

// ---------- constants ----------
#define B_  2
#define T_  4096
#define DM  2048
#define H_  16
#define HKV 4
#define DV_ 64
#define MB_ 64
#define LW_ 1024
#define REMOTE 3072     // T - LW
#define NBLK 48         // REMOTE/MB
#define KTOT 1072       // NBLK + LW
#define NTILES 17       // ceil(1072/64)

typedef __bf16 bf16x8 __attribute__((ext_vector_type(8)));
typedef float  f32x4  __attribute__((ext_vector_type(4)));

__device__ __forceinline__ float bf2f(unsigned short u) {
    unsigned int x = ((unsigned int)u) << 16;
    return __builtin_bit_cast(float, x);
}
__device__ __forceinline__ unsigned short f2bf(float f) {
    unsigned int x = __builtin_bit_cast(unsigned int, f);
    x = x + 0x7fffu + ((x >> 16) & 1u);   // round-to-nearest-even
    return (unsigned short)(x >> 16);
}

// ---------- fp32 -> bf16 bulk convert ----------
__global__ void cvt_f32_to_bf16(const float* __restrict__ src,
                                unsigned short* __restrict__ dst, int n) {
    int i = (blockIdx.x * blockDim.x + threadIdx.x) * 4;
    if (i >= n) return;
    float4 v = *(const float4*)(src + i);
    ushort4 o;
    o.x = f2bf(v.x); o.y = f2bf(v.y); o.z = f2bf(v.z); o.w = f2bf(v.w);
    *(ushort4*)(dst + i) = o;
}

// ---------- transpose + convert: src[R][C] f32 -> dst[C][R] bf16 ----------
__global__ void transpose_cvt(const float* __restrict__ src,
                              unsigned short* __restrict__ dst, int R, int C) {
    __shared__ float tile[32][33];
    int ct = blockIdx.x, rt = blockIdx.y;
    int tx = threadIdx.x, ty = threadIdx.y;
    #pragma unroll
    for (int i = ty; i < 32; i += 8)
        tile[i][tx] = src[(size_t)(rt * 32 + i) * C + ct * 32 + tx];
    __syncthreads();
    #pragma unroll
    for (int i = ty; i < 32; i += 8)
        dst[(size_t)(ct * 32 + i) * R + rt * 32 + tx] = f2bf(tile[tx][i]);
}

// ---------- bf16 MFMA GEMM, B pre-transposed: C[M,N] = A[M,K] * BT[N,K]^T ----
// MODE 0: scatter-epilogue into qcat/kcatf/vf (proj GEMM, N=1536)
// MODE 1: plain f32 store (Wo GEMM)
template<int MODE>
__global__ __launch_bounds__(256) void gemm_bt(
    const unsigned short* __restrict__ A,
    const unsigned short* __restrict__ BT,
    float* __restrict__ outF,
    unsigned short* __restrict__ qcat,
    unsigned short* __restrict__ kcatf,
    unsigned short* __restrict__ vf,
    int M, int N, int K)
{
    __shared__ unsigned short As[128][40];
    __shared__ unsigned short Bs[128][40];
    const int tid  = threadIdx.x;
    const int lane = tid & 63, wave = tid >> 6;
    const int wr = wave >> 1, wc = wave & 1;
    const int row0 = blockIdx.y * 128, col0 = blockIdx.x * 128;
    const int lr = lane & 15;
    f32x4 acc[4][4] = {};

    for (int kk = 0; kk < K; kk += 32) {
        #pragma unroll
        for (int c = tid; c < 512; c += 256) {
            int r = c >> 2, p = (c & 3) * 8;
            *(uint4*)&As[r][p] = *(const uint4*)&A [(size_t)(row0 + r) * K + kk + p];
            *(uint4*)&Bs[r][p] = *(const uint4*)&BT[(size_t)(col0 + r) * K + kk + p];
        }
        __syncthreads();
        bf16x8 af[4], bfr[4];
        int lk = (lane >> 4) * 8;
        #pragma unroll
        for (int mf = 0; mf < 4; mf++)
            af[mf] = __builtin_bit_cast(bf16x8, *(const uint4*)&As[wr*64 + mf*16 + lr][lk]);
        #pragma unroll
        for (int nf = 0; nf < 4; nf++)
            bfr[nf] = __builtin_bit_cast(bf16x8, *(const uint4*)&Bs[wc*64 + nf*16 + lr][lk]);
        #pragma unroll
        for (int mf = 0; mf < 4; mf++)
            #pragma unroll
            for (int nf = 0; nf < 4; nf++)
                acc[mf][nf] = __builtin_amdgcn_mfma_f32_16x16x32_bf16(
                                  af[mf], bfr[nf], acc[mf][nf], 0, 0, 0);
        __syncthreads();
    }

    const int r0 = (lane >> 4) * 4, c0 = lane & 15;
    #pragma unroll
    for (int mf = 0; mf < 4; mf++) {
        #pragma unroll
        for (int nf = 0; nf < 4; nf++) {
            #pragma unroll
            for (int r = 0; r < 4; r++) {
                int row = row0 + wr*64 + mf*16 + r0 + r;
                int col = col0 + wc*64 + nf*16 + c0;
                float v = acc[mf][nf][r];
                if (MODE == 1) {
                    outF[(size_t)row * N + col] = v;
                } else {
                    int b = row >> 12, t = row & 4095;
                    unsigned short hv = f2bf(v);
                    if (col < 512) {                       // q_sem
                        int h = col >> 5, d = col & 31;
                        qcat[(((size_t)(b*16 + h))*4096 + t)*64 + d] = hv;
                    } else if (col < 1024) {               // q_geo
                        int c2 = col - 512; int h = c2 >> 5, d = c2 & 31;
                        qcat[(((size_t)(b*16 + h))*4096 + t)*64 + 32 + d] = hv;
                    } else if (col < 1152) {               // k_sem
                        int c2 = col - 1024; int g = c2 >> 5, d = c2 & 31;
                        kcatf[(((size_t)(b*4 + g))*4096 + t)*64 + d] = hv;
                    } else if (col < 1280) {               // k_geo
                        int c2 = col - 1152; int g = c2 >> 5, d = c2 & 31;
                        kcatf[(((size_t)(b*4 + g))*4096 + t)*64 + 32 + d] = hv;
                    } else {                               // v
                        int c2 = col - 1280; int g = c2 >> 6, d = c2 & 63;
                        vf[(((size_t)(b*4 + g))*4096 + t)*64 + d] = hv;
                    }
                }
            }
        }
    }
}

// ---------- RoPE rotate (in-place, dims 32..63 of each 64-dim row) ----------
__global__ void rope_rotate(unsigned short* __restrict__ buf, int nrows, int T) {
    int idx = blockIdx.x * 256 + threadIdx.x;
    int row = idx >> 4, i = idx & 15;
    if (row >= nrows) return;
    int t = row % T;
    float inv = exp2f(-(float)i * 0.8304820237218406f);   // 10000^(-i/16)
    float ang = (float)t * inv;
    float s, c;
    sincosf(ang, &s, &c);
    unsigned short* p = buf + (size_t)row * 64;
    float g1 = bf2f(p[32 + i]), g2 = bf2f(p[48 + i]);
    p[32 + i] = f2bf(g1 * c - g2 * s);
    p[48 + i] = f2bf(g2 * c + g1 * s);
}

// ---------- mem-block pooling: full-res KV -> 1072 summarized keys ----------
// kp: [bg][key][64] row-major.  vt: [bg][d][key] TRANSPOSED (for direct B-frags).
__global__ void pool_kv(const unsigned short* __restrict__ kf,
                        const unsigned short* __restrict__ vfull,
                        unsigned short* __restrict__ kp,
                        unsigned short* __restrict__ vt) {
    int key = blockIdx.x % KTOT;
    int bg  = blockIdx.x / KTOT;
    int d = threadIdx.x;
    size_t srcbase = (size_t)bg * T_ * 64;
    size_t kdst = ((size_t)bg * KTOT + key) * 64 + d;
    size_t vdst = ((size_t)bg * 64 + d) * KTOT + key;
    if (key < NBLK) {
        float sk = 0.f, sv = 0.f;
        for (int j = 0; j < MB_; j++) {
            size_t o = srcbase + (size_t)(key * MB_ + j) * 64 + d;
            sk += bf2f(kf[o]);
            sv += bf2f(vfull[o]);
        }
        kp[kdst] = f2bf(sk * (1.f / 64.f));
        vt[vdst] = f2bf(sv * (1.f / 64.f));
    } else {
        int t = REMOTE + key - NBLK;
        size_t o = srcbase + (size_t)t * 64 + d;
        kp[kdst] = kf[o];
        vt[vdst] = vfull[o];
    }
}

// ---------- MFMA flash attention, wave-independent (NO barriers) ----------
// 4096 waves; each wave owns 32 queries of one (h,b). K/V read directly from
// the L2-resident pooled buffers into MFMA B-frags. P goes through wave-
// private LDS. Heavy units (q<64 uniform rows + large-q) scheduled first.
__global__ __launch_bounds__(256) void attn_fwd(
    const unsigned short* __restrict__ qcat,
    const unsigned short* __restrict__ kp,   // [bg][key][64]
    const unsigned short* __restrict__ vt,   // [bg][d][KTOT]
    const float* __restrict__ ls,
    unsigned short* __restrict__ attn_out)
{
    __shared__ unsigned short Pl[4][32][72];   // per-wave P tile (bf16)

    const int tid = threadIdx.x;
    const int lane = tid & 63, w = tid >> 6;
    const int l15 = lane & 15, lg = lane >> 4;

    const int wid = blockIdx.x * 4 + w;        // 0..4095
    const int hb = wid & 31;
    const int iu = wid >> 5;                   // schedule slot 0..127
    // heavy-first bijection: slots 0..31 -> units 127..96, 32->0, 33->1,
    // 34..127 -> units 2..95
    int i;
    if (iu < 32)       i = 127 - iu;
    else if (iu == 32) i = 0;
    else if (iu == 33) i = 1;
    else               i = iu - 32;
    const int h = hb & 15, b = hb >> 4, g = h >> 2;
    const int q0 = i * 32;

    // number of 64-key tiles this unit needs
    int ktmax;
    if (q0 < 64) ktmax = NTILES;               // uniform rows: all keys
    else {
        int lastkey = q0 + 31 - 3024;          // max valid local key index
        ktmax = (lastkey < NBLK) ? 1 : (lastkey / 64 + 1);
    }

    const float sc = __expf(ls[h]) * 0.17677669529663687f;   // exp(ls)/sqrt(32)

    // Q A-fragments: aq[rowfrag][khalf]
    bf16x8 aq[2][2];
    const unsigned short* qbase = qcat + (((size_t)(b * 16 + h)) * T_ + q0) * 64;
    #pragma unroll
    for (int rf = 0; rf < 2; rf++)
        #pragma unroll
        for (int kh = 0; kh < 2; kh++)
            aq[rf][kh] = __builtin_bit_cast(bf16x8,
                *(const uint4*)(qbase + (size_t)(rf*16 + l15)*64 + kh*32 + lg*8));

    float m[2][4], lrun[2][4];
    #pragma unroll
    for (int rf = 0; rf < 2; rf++)
        #pragma unroll
        for (int r = 0; r < 4; r++) { m[rf][r] = -1e9f; lrun[rf][r] = 0.f; }
    f32x4 oacc[2][4] = {};

    const unsigned short* kbase = kp + ((size_t)(b * 4 + g)) * KTOT * 64;
    const unsigned short* vbase = vt + ((size_t)(b * 4 + g)) * 64 * KTOT;

    for (int kt = 0; kt < ktmax; kt++) {
        const int kb = kt * 64;

        // ---- K B-frags direct from global (row [key][64], 16B per lane) ----
        bf16x8 bk[4][2];
        #pragma unroll
        for (int nf = 0; nf < 4; nf++) {
            int krow = kb + nf*16 + l15;
            int krc = krow < KTOT ? krow : KTOT - 1;     // clamp (masked later)
            #pragma unroll
            for (int kh = 0; kh < 2; kh++)
                bk[nf][kh] = __builtin_bit_cast(bf16x8,
                    *(const uint4*)(kbase + (size_t)krc * 64 + kh*32 + lg*8));
        }

        // ---- QK^T: S[32q][64k] ----
        f32x4 s[2][4] = {};
        #pragma unroll
        for (int rf = 0; rf < 2; rf++)
            #pragma unroll
            for (int nf = 0; nf < 4; nf++)
                #pragma unroll
                for (int kh = 0; kh < 2; kh++)
                    s[rf][nf] = __builtin_amdgcn_mfma_f32_16x16x32_bf16(
                                    aq[rf][kh], bk[nf][kh], s[rf][nf], 0, 0, 0);

        // ---- V B-frags direct from global ([d][key], 16B per lane) ----
        bf16x8 bv[4][2];
        #pragma unroll
        for (int nfv = 0; nfv < 4; nfv++)
            #pragma unroll
            for (int kh = 0; kh < 2; kh++) {
                int kc = kb + kh*32 + lg*8;
                int kcc = (kc + 8 <= KTOT) ? kc : KTOT - 8;  // clamp (P=0 there)
                bv[nfv][kh] = __builtin_bit_cast(bf16x8,
                    *(const uint4*)(vbase + (size_t)(nfv*16 + l15) * KTOT + kcc));
            }

        // ---- mask + wave-parallel online softmax + P->LDS ----
        #pragma unroll
        for (int rf = 0; rf < 2; rf++) {
            #pragma unroll
            for (int r = 0; r < 4; r++) {
                const int qpos = q0 + rf*16 + lg*4 + r;
                float vals[4];
                float tmax = -INFINITY;
                #pragma unroll
                for (int nf = 0; nf < 4; nf++) {
                    int key = kb + nf*16 + l15;
                    float v = s[rf][nf][r] * sc;
                    int kpos = (key < NBLK) ? key * 64 + 63 : 3024 + key;
                    v = (key < KTOT) ? ((kpos <= qpos) ? v : -1e9f) : -INFINITY;
                    vals[nf] = v;
                    tmax = fmaxf(tmax, v);
                }
                #pragma unroll
                for (int d = 1; d < 16; d <<= 1)
                    tmax = fmaxf(tmax, __shfl_xor(tmax, d));
                float mn = fmaxf(m[rf][r], tmax);
                float scl = __expf(m[rf][r] - mn);
                m[rf][r] = mn;
                float rs = 0.f;
                #pragma unroll
                for (int nf = 0; nf < 4; nf++) {
                    unsigned short pb = f2bf(__expf(vals[nf] - mn));
                    rs += bf2f(pb);          // sum the ROUNDED p: exact convex comb
                    Pl[w][rf*16 + lg*4 + r][nf*16 + l15] = pb;
                }
                #pragma unroll
                for (int d = 1; d < 16; d <<= 1)
                    rs += __shfl_xor(rs, d);
                lrun[rf][r] = lrun[rf][r] * scl + rs;
                #pragma unroll
                for (int nfv = 0; nfv < 4; nfv++)
                    oacc[rf][nfv][r] *= scl;
            }
        }

        // ---- PV: O += P V  (Pl wave-private; no barrier) ----
        #pragma unroll
        for (int rf = 0; rf < 2; rf++) {
            bf16x8 pa[2];
            #pragma unroll
            for (int kh = 0; kh < 2; kh++)
                pa[kh] = __builtin_bit_cast(bf16x8,
                    *(const uint4*)&Pl[w][rf*16 + l15][kh*32 + lg*8]);
            #pragma unroll
            for (int nfv = 0; nfv < 4; nfv++)
                #pragma unroll
                for (int kh = 0; kh < 2; kh++)
                    oacc[rf][nfv] = __builtin_amdgcn_mfma_f32_16x16x32_bf16(
                                        pa[kh], bv[nfv][kh], oacc[rf][nfv], 0, 0, 0);
        }
    }

    // ---- epilogue: normalize and store ----
    #pragma unroll
    for (int rf = 0; rf < 2; rf++) {
        #pragma unroll
        for (int r = 0; r < 4; r++) {
            float inv = 1.f / lrun[rf][r];
            int q = q0 + rf*16 + lg*4 + r;
            size_t obase = ((size_t)(b * T_ + q)) * 1024 + h * 64;
            #pragma unroll
            for (int nfv = 0; nfv < 4; nfv++)
                attn_out[obase + nfv*16 + l15] = f2bf(oacc[rf][nfv][r] * inv);
        }
    }
}

// ---------- host launch ----------
extern "C" void kernel_launch(void* const* d_in, const int* in_sizes, int n_in,
                              void* d_out, int out_size, void* d_ws, size_t ws_size,
                              hipStream_t stream) {
    const float* x      = (const float*)d_in[0];
    const float* Wq_sem = (const float*)d_in[1];
    const float* Wk_sem = (const float*)d_in[2];
    const float* Wq_geo = (const float*)d_in[3];
    const float* Wk_geo = (const float*)d_in[4];
    const float* Wv     = (const float*)d_in[5];
    const float* Wo     = (const float*)d_in[6];
    const float* ls     = (const float*)d_in[7];

    char* w = (char*)d_ws;
    auto alloc = [&](size_t bytes) {
        char* p = w;
        w += (bytes + 255) & ~(size_t)255;
        return p;
    };
    unsigned short* xb    = (unsigned short*)alloc((size_t)8192 * 2048 * 2);
    unsigned short* WcatT = (unsigned short*)alloc((size_t)1536 * 2048 * 2);
    unsigned short* WoT   = (unsigned short*)alloc((size_t)2048 * 1024 * 2);
    unsigned short* qcat  = (unsigned short*)alloc((size_t)2 * 16 * 4096 * 64 * 2);
    unsigned short* kcatf = (unsigned short*)alloc((size_t)2 * 4 * 4096 * 64 * 2);
    unsigned short* vfull = (unsigned short*)alloc((size_t)2 * 4 * 4096 * 64 * 2);
    unsigned short* kcatp = (unsigned short*)alloc((size_t)2 * 4 * 1072 * 64 * 2);
    unsigned short* vpool = (unsigned short*)alloc((size_t)2 * 4 * 1072 * 64 * 2);
    unsigned short* aout  = (unsigned short*)alloc((size_t)8192 * 1024 * 2);

    // 1) x -> bf16
    cvt_f32_to_bf16<<<16384, 256, 0, stream>>>(x, xb, 8192 * 2048);

    // 2) weights -> bf16, transposed to [N][K]
    dim3 tb(32, 8);
    transpose_cvt<<<dim3(16, 64), tb, 0, stream>>>(Wq_sem, WcatT + (size_t)0    * 2048, 2048, 512);
    transpose_cvt<<<dim3(16, 64), tb, 0, stream>>>(Wq_geo, WcatT + (size_t)512  * 2048, 2048, 512);
    transpose_cvt<<<dim3( 4, 64), tb, 0, stream>>>(Wk_sem, WcatT + (size_t)1024 * 2048, 2048, 128);
    transpose_cvt<<<dim3( 4, 64), tb, 0, stream>>>(Wk_geo, WcatT + (size_t)1152 * 2048, 2048, 128);
    transpose_cvt<<<dim3( 8, 64), tb, 0, stream>>>(Wv,     WcatT + (size_t)1280 * 2048, 2048, 256);
    transpose_cvt<<<dim3(64, 32), tb, 0, stream>>>(Wo, WoT, 1024, 2048);

    // 3) fused projection GEMM -> qcat / kcatf / vfull (bf16)
    gemm_bt<0><<<dim3(12, 64), 256, 0, stream>>>(
        xb, WcatT, nullptr, qcat, kcatf, vfull, 8192, 1536, 2048);

    // 4) RoPE on geo halves
    rope_rotate<<<8192, 256, 0, stream>>>(qcat, 2 * 16 * 4096, 4096);
    rope_rotate<<<2048, 256, 0, stream>>>(kcatf, 2 * 4 * 4096, 4096);

    // 5) memory-block pooling (K row-major, V transposed)
    pool_kv<<<8 * KTOT, 64, 0, stream>>>(kcatf, vfull, kcatp, vpool);

    // 6) wave-independent MFMA flash attention
    attn_fwd<<<dim3(1024), 256, 0, stream>>>(qcat, kcatp, vpool, ls, aout);

    // 7) output projection -> d_out (fp32)
    gemm_bt<1><<<dim3(16, 64), 256, 0, stream>>>(
        aout, WoT, (float*)d_out, nullptr, nullptr, nullptr, 8192, 2048, 1024);
}

// Round 5
// 269.557 us; speedup vs baseline: 2.8810x; 1.0651x over previous
//
#include <hip/hip_runtime.h>
#include <math.h>

// ---------- constants ----------
#define B_  2
#define T_  4096
#define DM  2048
#define H_  16
#define HKV 4
#define DV_ 64
#define MB_ 64
#define LW_ 1024
#define REMOTE 3072     // T - LW
#define NBLK 48         // REMOTE/MB
#define KTOT 1072       // NBLK + LW
#define NTILES 17       // ceil(1072/64)

typedef __bf16 bf16x8 __attribute__((ext_vector_type(8)));
typedef float  f32x4  __attribute__((ext_vector_type(4)));

__device__ __forceinline__ float bf2f(unsigned short u) {
    unsigned int x = ((unsigned int)u) << 16;
    return __builtin_bit_cast(float, x);
}
__device__ __forceinline__ unsigned short f2bf(float f) {
    unsigned int x = __builtin_bit_cast(unsigned int, f);
    x = x + 0x7fffu + ((x >> 16) & 1u);   // round-to-nearest-even
    return (unsigned short)(x >> 16);
}

// async global->LDS, 16B per lane; LDS dest = wave-uniform base + lane*16
__device__ __forceinline__ void gload16(const unsigned short* gsrc,
                                        unsigned short* ldst) {
    __builtin_amdgcn_global_load_lds(
        (const __attribute__((address_space(1))) void*)gsrc,
        (__attribute__((address_space(3))) void*)ldst,
        16, 0, 0);
}

// ---------- fp32 -> bf16 bulk convert ----------
__global__ void cvt_f32_to_bf16(const float* __restrict__ src,
                                unsigned short* __restrict__ dst, int n) {
    int i = (blockIdx.x * blockDim.x + threadIdx.x) * 4;
    if (i >= n) return;
    float4 v = *(const float4*)(src + i);
    ushort4 o;
    o.x = f2bf(v.x); o.y = f2bf(v.y); o.z = f2bf(v.z); o.w = f2bf(v.w);
    *(ushort4*)(dst + i) = o;
}

// ---------- transpose + convert: src[R][C] f32 -> dst[C][R] bf16 ----------
__global__ void transpose_cvt(const float* __restrict__ src,
                              unsigned short* __restrict__ dst, int R, int C) {
    __shared__ float tile[32][33];
    int ct = blockIdx.x, rt = blockIdx.y;
    int tx = threadIdx.x, ty = threadIdx.y;
    #pragma unroll
    for (int i = ty; i < 32; i += 8)
        tile[i][tx] = src[(size_t)(rt * 32 + i) * C + ct * 32 + tx];
    __syncthreads();
    #pragma unroll
    for (int i = ty; i < 32; i += 8)
        dst[(size_t)(ct * 32 + i) * R + rt * 32 + tx] = f2bf(tile[tx][i]);
}

// ---------- bf16 MFMA GEMM (m97 structure), B pre-transposed --------------
// C[M,N] = A[M,K] * BT[N,K]^T.  128x128 tile, BK=32, 4 waves (2x2), linear
// LDS staged via global_load_lds width=16, XCD-swizzled 1D grid.
// MODE 0: scatter-epilogue into qcat/kcatf/vf (proj GEMM, N=1536)
// MODE 1: plain f32 store (Wo GEMM)
template<int MODE>
__global__ __launch_bounds__(256) void gemm_bt(
    const unsigned short* __restrict__ A,
    const unsigned short* __restrict__ BT,
    float* __restrict__ outF,
    unsigned short* __restrict__ qcat,
    unsigned short* __restrict__ kcatf,
    unsigned short* __restrict__ vf,
    int M, int N, int K, int nbx)
{
    __shared__ unsigned short As[128 * 32];   // linear, NO padding (gload_lds)
    __shared__ unsigned short Bs[128 * 32];

    const int tid  = threadIdx.x;
    const int lane = tid & 63, w = tid >> 6;
    const int wr = w >> 1, wc = w & 1;

    // bijective XCD swizzle (gridDim.x % 8 == 0): each XCD gets a contiguous
    // chunk of swz ids -> consecutive col-blocks of the same row-panel.
    const int qq  = gridDim.x >> 3;
    const int swz = (blockIdx.x & 7) * qq + (blockIdx.x >> 3);
    const int bx = swz % nbx, by = swz / nbx;
    const int row0 = by * 128, col0 = bx * 128;

    const int lr = lane & 15, lk = (lane >> 4) * 8;

    // staging geometry: chunk i = (s*4+w)*64 + lane covers LDS elems 8i..8i+7
    // = tile row r=i>>2, cols (i&3)*8 .. +8
    const int i0 = w * 64 + lane, i1 = i0 + 256;
    const int ra = i0 >> 2, ca = (i0 & 3) * 8;
    const int rb = i1 >> 2, cb = (i1 & 3) * 8;
    unsigned short* ldsA0 = &As[(size_t)w * 512];
    unsigned short* ldsA1 = &As[(size_t)(4 + w) * 512];
    unsigned short* ldsB0 = &Bs[(size_t)w * 512];
    unsigned short* ldsB1 = &Bs[(size_t)(4 + w) * 512];
    const unsigned short* Abase = A  + (size_t)row0 * K;
    const unsigned short* Bbase = BT + (size_t)col0 * K;

    f32x4 acc[4][4] = {};

    for (int kk = 0; kk < K; kk += 32) {
        gload16(Abase + (size_t)ra * K + kk + ca, ldsA0);
        gload16(Abase + (size_t)rb * K + kk + cb, ldsA1);
        gload16(Bbase + (size_t)ra * K + kk + ca, ldsB0);
        gload16(Bbase + (size_t)rb * K + kk + cb, ldsB1);
        __syncthreads();   // compiler drains vmcnt(0) before s_barrier

        bf16x8 af[4], bfr[4];
        #pragma unroll
        for (int mf = 0; mf < 4; mf++)
            af[mf] = __builtin_bit_cast(bf16x8,
                *(const uint4*)&As[(wr*64 + mf*16 + lr) * 32 + lk]);
        #pragma unroll
        for (int nf = 0; nf < 4; nf++)
            bfr[nf] = __builtin_bit_cast(bf16x8,
                *(const uint4*)&Bs[(wc*64 + nf*16 + lr) * 32 + lk]);
        #pragma unroll
        for (int mf = 0; mf < 4; mf++)
            #pragma unroll
            for (int nf = 0; nf < 4; nf++)
                acc[mf][nf] = __builtin_amdgcn_mfma_f32_16x16x32_bf16(
                                  af[mf], bfr[nf], acc[mf][nf], 0, 0, 0);
        __syncthreads();   // protect LDS before next stage
    }

    const int r0 = (lane >> 4) * 4, c0 = lane & 15;
    #pragma unroll
    for (int mf = 0; mf < 4; mf++) {
        #pragma unroll
        for (int nf = 0; nf < 4; nf++) {
            #pragma unroll
            for (int r = 0; r < 4; r++) {
                int row = row0 + wr*64 + mf*16 + r0 + r;
                int col = col0 + wc*64 + nf*16 + c0;
                float v = acc[mf][nf][r];
                if (MODE == 1) {
                    outF[(size_t)row * N + col] = v;
                } else {
                    int b = row >> 12, t = row & 4095;
                    unsigned short hv = f2bf(v);
                    if (col < 512) {                       // q_sem
                        int h = col >> 5, d = col & 31;
                        qcat[(((size_t)(b*16 + h))*4096 + t)*64 + d] = hv;
                    } else if (col < 1024) {               // q_geo
                        int c2 = col - 512; int h = c2 >> 5, d = c2 & 31;
                        qcat[(((size_t)(b*16 + h))*4096 + t)*64 + 32 + d] = hv;
                    } else if (col < 1152) {               // k_sem
                        int c2 = col - 1024; int g = c2 >> 5, d = c2 & 31;
                        kcatf[(((size_t)(b*4 + g))*4096 + t)*64 + d] = hv;
                    } else if (col < 1280) {               // k_geo
                        int c2 = col - 1152; int g = c2 >> 5, d = c2 & 31;
                        kcatf[(((size_t)(b*4 + g))*4096 + t)*64 + 32 + d] = hv;
                    } else {                               // v
                        int c2 = col - 1280; int g = c2 >> 6, d = c2 & 63;
                        vf[(((size_t)(b*4 + g))*4096 + t)*64 + d] = hv;
                    }
                }
            }
        }
    }
}

// ---------- RoPE rotate (in-place, dims 32..63 of each 64-dim row) ----------
__global__ void rope_rotate(unsigned short* __restrict__ buf, int nrows, int T) {
    int idx = blockIdx.x * 256 + threadIdx.x;
    int row = idx >> 4, i = idx & 15;
    if (row >= nrows) return;
    int t = row % T;
    float inv = exp2f(-(float)i * 0.8304820237218406f);   // 10000^(-i/16)
    float ang = (float)t * inv;
    float s, c;
    sincosf(ang, &s, &c);
    unsigned short* p = buf + (size_t)row * 64;
    float g1 = bf2f(p[32 + i]), g2 = bf2f(p[48 + i]);
    p[32 + i] = f2bf(g1 * c - g2 * s);
    p[48 + i] = f2bf(g2 * c + g1 * s);
}

// ---------- mem-block pooling: full-res KV -> 1072 summarized keys ----------
// kp: [bg][key][64] row-major.  vt: [bg][d][key] TRANSPOSED (for direct B-frags).
__global__ void pool_kv(const unsigned short* __restrict__ kf,
                        const unsigned short* __restrict__ vfull,
                        unsigned short* __restrict__ kp,
                        unsigned short* __restrict__ vt) {
    int key = blockIdx.x % KTOT;
    int bg  = blockIdx.x / KTOT;
    int d = threadIdx.x;
    size_t srcbase = (size_t)bg * T_ * 64;
    size_t kdst = ((size_t)bg * KTOT + key) * 64 + d;
    size_t vdst = ((size_t)bg * 64 + d) * KTOT + key;
    if (key < NBLK) {
        float sk = 0.f, sv = 0.f;
        for (int j = 0; j < MB_; j++) {
            size_t o = srcbase + (size_t)(key * MB_ + j) * 64 + d;
            sk += bf2f(kf[o]);
            sv += bf2f(vfull[o]);
        }
        kp[kdst] = f2bf(sk * (1.f / 64.f));
        vt[vdst] = f2bf(sv * (1.f / 64.f));
    } else {
        int t = REMOTE + key - NBLK;
        size_t o = srcbase + (size_t)t * 64 + d;
        kp[kdst] = kf[o];
        vt[vdst] = vfull[o];
    }
}

// ---------- MFMA flash attention, wave-independent (NO barriers) ----------
__global__ __launch_bounds__(256) void attn_fwd(
    const unsigned short* __restrict__ qcat,
    const unsigned short* __restrict__ kp,   // [bg][key][64]
    const unsigned short* __restrict__ vt,   // [bg][d][KTOT]
    const float* __restrict__ ls,
    unsigned short* __restrict__ attn_out)
{
    __shared__ unsigned short Pl[4][32][72];   // per-wave P tile (bf16)

    const int tid = threadIdx.x;
    const int lane = tid & 63, w = tid >> 6;
    const int l15 = lane & 15, lg = lane >> 4;

    const int wid = blockIdx.x * 4 + w;        // 0..4095
    const int hb = wid & 31;
    const int iu = wid >> 5;                   // schedule slot 0..127
    int i;
    if (iu < 32)       i = 127 - iu;
    else if (iu == 32) i = 0;
    else if (iu == 33) i = 1;
    else               i = iu - 32;
    const int h = hb & 15, b = hb >> 4, g = h >> 2;
    const int q0 = i * 32;

    int ktmax;
    if (q0 < 64) ktmax = NTILES;               // uniform rows: all keys
    else {
        int lastkey = q0 + 31 - 3024;          // max valid local key index
        ktmax = (lastkey < NBLK) ? 1 : (lastkey / 64 + 1);
    }

    const float sc = __expf(ls[h]) * 0.17677669529663687f;   // exp(ls)/sqrt(32)

    bf16x8 aq[2][2];
    const unsigned short* qbase = qcat + (((size_t)(b * 16 + h)) * T_ + q0) * 64;
    #pragma unroll
    for (int rf = 0; rf < 2; rf++)
        #pragma unroll
        for (int kh = 0; kh < 2; kh++)
            aq[rf][kh] = __builtin_bit_cast(bf16x8,
                *(const uint4*)(qbase + (size_t)(rf*16 + l15)*64 + kh*32 + lg*8));

    float m[2][4], lrun[2][4];
    #pragma unroll
    for (int rf = 0; rf < 2; rf++)
        #pragma unroll
        for (int r = 0; r < 4; r++) { m[rf][r] = -1e9f; lrun[rf][r] = 0.f; }
    f32x4 oacc[2][4] = {};

    const unsigned short* kbase = kp + ((size_t)(b * 4 + g)) * KTOT * 64;
    const unsigned short* vbase = vt + ((size_t)(b * 4 + g)) * 64 * KTOT;

    for (int kt = 0; kt < ktmax; kt++) {
        const int kb = kt * 64;

        bf16x8 bk[4][2];
        #pragma unroll
        for (int nf = 0; nf < 4; nf++) {
            int krow = kb + nf*16 + l15;
            int krc = krow < KTOT ? krow : KTOT - 1;     // clamp (masked later)
            #pragma unroll
            for (int kh = 0; kh < 2; kh++)
                bk[nf][kh] = __builtin_bit_cast(bf16x8,
                    *(const uint4*)(kbase + (size_t)krc * 64 + kh*32 + lg*8));
        }

        f32x4 s[2][4] = {};
        #pragma unroll
        for (int rf = 0; rf < 2; rf++)
            #pragma unroll
            for (int nf = 0; nf < 4; nf++)
                #pragma unroll
                for (int kh = 0; kh < 2; kh++)
                    s[rf][nf] = __builtin_amdgcn_mfma_f32_16x16x32_bf16(
                                    aq[rf][kh], bk[nf][kh], s[rf][nf], 0, 0, 0);

        bf16x8 bv[4][2];
        #pragma unroll
        for (int nfv = 0; nfv < 4; nfv++)
            #pragma unroll
            for (int kh = 0; kh < 2; kh++) {
                int kc = kb + kh*32 + lg*8;
                int kcc = (kc + 8 <= KTOT) ? kc : KTOT - 8;  // clamp (P=0 there)
                bv[nfv][kh] = __builtin_bit_cast(bf16x8,
                    *(const uint4*)(vbase + (size_t)(nfv*16 + l15) * KTOT + kcc));
            }

        #pragma unroll
        for (int rf = 0; rf < 2; rf++) {
            #pragma unroll
            for (int r = 0; r < 4; r++) {
                const int qpos = q0 + rf*16 + lg*4 + r;
                float vals[4];
                float tmax = -INFINITY;
                #pragma unroll
                for (int nf = 0; nf < 4; nf++) {
                    int key = kb + nf*16 + l15;
                    float v = s[rf][nf][r] * sc;
                    int kpos = (key < NBLK) ? key * 64 + 63 : 3024 + key;
                    v = (key < KTOT) ? ((kpos <= qpos) ? v : -1e9f) : -INFINITY;
                    vals[nf] = v;
                    tmax = fmaxf(tmax, v);
                }
                #pragma unroll
                for (int d = 1; d < 16; d <<= 1)
                    tmax = fmaxf(tmax, __shfl_xor(tmax, d));
                float mn = fmaxf(m[rf][r], tmax);
                float scl = __expf(m[rf][r] - mn);
                m[rf][r] = mn;
                float rs = 0.f;
                #pragma unroll
                for (int nf = 0; nf < 4; nf++) {
                    unsigned short pb = f2bf(__expf(vals[nf] - mn));
                    rs += bf2f(pb);          // sum the ROUNDED p: exact convex comb
                    Pl[w][rf*16 + lg*4 + r][nf*16 + l15] = pb;
                }
                #pragma unroll
                for (int d = 1; d < 16; d <<= 1)
                    rs += __shfl_xor(rs, d);
                lrun[rf][r] = lrun[rf][r] * scl + rs;
                #pragma unroll
                for (int nfv = 0; nfv < 4; nfv++)
                    oacc[rf][nfv][r] *= scl;
            }
        }

        #pragma unroll
        for (int rf = 0; rf < 2; rf++) {
            bf16x8 pa[2];
            #pragma unroll
            for (int kh = 0; kh < 2; kh++)
                pa[kh] = __builtin_bit_cast(bf16x8,
                    *(const uint4*)&Pl[w][rf*16 + l15][kh*32 + lg*8]);
            #pragma unroll
            for (int nfv = 0; nfv < 4; nfv++)
                #pragma unroll
                for (int kh = 0; kh < 2; kh++)
                    oacc[rf][nfv] = __builtin_amdgcn_mfma_f32_16x16x32_bf16(
                                        pa[kh], bv[nfv][kh], oacc[rf][nfv], 0, 0, 0);
        }
    }

    #pragma unroll
    for (int rf = 0; rf < 2; rf++) {
        #pragma unroll
        for (int r = 0; r < 4; r++) {
            float inv = 1.f / lrun[rf][r];
            int q = q0 + rf*16 + lg*4 + r;
            size_t obase = ((size_t)(b * T_ + q)) * 1024 + h * 64;
            #pragma unroll
            for (int nfv = 0; nfv < 4; nfv++)
                attn_out[obase + nfv*16 + l15] = f2bf(oacc[rf][nfv][r] * inv);
        }
    }
}

// ---------- host launch ----------
extern "C" void kernel_launch(void* const* d_in, const int* in_sizes, int n_in,
                              void* d_out, int out_size, void* d_ws, size_t ws_size,
                              hipStream_t stream) {
    const float* x      = (const float*)d_in[0];
    const float* Wq_sem = (const float*)d_in[1];
    const float* Wk_sem = (const float*)d_in[2];
    const float* Wq_geo = (const float*)d_in[3];
    const float* Wk_geo = (const float*)d_in[4];
    const float* Wv     = (const float*)d_in[5];
    const float* Wo     = (const float*)d_in[6];
    const float* ls     = (const float*)d_in[7];

    char* w = (char*)d_ws;
    auto alloc = [&](size_t bytes) {
        char* p = w;
        w += (bytes + 255) & ~(size_t)255;
        return p;
    };
    unsigned short* xb    = (unsigned short*)alloc((size_t)8192 * 2048 * 2);
    unsigned short* WcatT = (unsigned short*)alloc((size_t)1536 * 2048 * 2);
    unsigned short* WoT   = (unsigned short*)alloc((size_t)2048 * 1024 * 2);
    unsigned short* qcat  = (unsigned short*)alloc((size_t)2 * 16 * 4096 * 64 * 2);
    unsigned short* kcatf = (unsigned short*)alloc((size_t)2 * 4 * 4096 * 64 * 2);
    unsigned short* vfull = (unsigned short*)alloc((size_t)2 * 4 * 4096 * 64 * 2);
    unsigned short* kcatp = (unsigned short*)alloc((size_t)2 * 4 * 1072 * 64 * 2);
    unsigned short* vpool = (unsigned short*)alloc((size_t)2 * 4 * 1072 * 64 * 2);
    unsigned short* aout  = (unsigned short*)alloc((size_t)8192 * 1024 * 2);

    // 1) x -> bf16
    cvt_f32_to_bf16<<<16384, 256, 0, stream>>>(x, xb, 8192 * 2048);

    // 2) weights -> bf16, transposed to [N][K]
    dim3 tb(32, 8);
    transpose_cvt<<<dim3(16, 64), tb, 0, stream>>>(Wq_sem, WcatT + (size_t)0    * 2048, 2048, 512);
    transpose_cvt<<<dim3(16, 64), tb, 0, stream>>>(Wq_geo, WcatT + (size_t)512  * 2048, 2048, 512);
    transpose_cvt<<<dim3( 4, 64), tb, 0, stream>>>(Wk_sem, WcatT + (size_t)1024 * 2048, 2048, 128);
    transpose_cvt<<<dim3( 4, 64), tb, 0, stream>>>(Wk_geo, WcatT + (size_t)1152 * 2048, 2048, 128);
    transpose_cvt<<<dim3( 8, 64), tb, 0, stream>>>(Wv,     WcatT + (size_t)1280 * 2048, 2048, 256);
    transpose_cvt<<<dim3(64, 32), tb, 0, stream>>>(Wo, WoT, 1024, 2048);

    // 3) fused projection GEMM -> qcat / kcatf / vfull (bf16)
    gemm_bt<0><<<768, 256, 0, stream>>>(
        xb, WcatT, nullptr, qcat, kcatf, vfull, 8192, 1536, 2048, 12);

    // 4) RoPE on geo halves
    rope_rotate<<<8192, 256, 0, stream>>>(qcat, 2 * 16 * 4096, 4096);
    rope_rotate<<<2048, 256, 0, stream>>>(kcatf, 2 * 4 * 4096, 4096);

    // 5) memory-block pooling (K row-major, V transposed)
    pool_kv<<<8 * KTOT, 64, 0, stream>>>(kcatf, vfull, kcatp, vpool);

    // 6) wave-independent MFMA flash attention
    attn_fwd<<<dim3(1024), 256, 0, stream>>>(qcat, kcatp, vpool, ls, aout);

    // 7) output projection -> d_out (fp32)
    gemm_bt<1><<<1024, 256, 0, stream>>>(
        aout, WoT, (float*)d_out, nullptr, nullptr, nullptr, 8192, 2048, 1024, 16);
}

// Round 6
// 221.651 us; speedup vs baseline: 3.5037x; 1.2161x over previous
//
#include <hip/hip_runtime.h>
#include <math.h>

// ---------- constants ----------
#define B_  2
#define T_  4096
#define DM  2048
#define H_  16
#define HKV 4
#define DV_ 64
#define MB_ 64
#define LW_ 1024
#define REMOTE 3072     // T - LW
#define NBLK 48         // REMOTE/MB
#define KTOT 1072       // NBLK + LW
#define NTILES 17       // ceil(1072/64)

typedef __bf16 bf16x8 __attribute__((ext_vector_type(8)));
typedef float  f32x4  __attribute__((ext_vector_type(4)));

__device__ __forceinline__ float bf2f(unsigned short u) {
    unsigned int x = ((unsigned int)u) << 16;
    return __builtin_bit_cast(float, x);
}
__device__ __forceinline__ unsigned short f2bf(float f) {
    unsigned int x = __builtin_bit_cast(unsigned int, f);
    x = x + 0x7fffu + ((x >> 16) & 1u);   // round-to-nearest-even
    return (unsigned short)(x >> 16);
}

// async global->LDS, 16B per lane; LDS dest = wave-uniform base + lane*16
__device__ __forceinline__ void gload16(const unsigned short* gsrc,
                                        unsigned short* ldst) {
    __builtin_amdgcn_global_load_lds(
        (const __attribute__((address_space(1))) void*)gsrc,
        (__attribute__((address_space(3))) void*)ldst,
        16, 0, 0);
}

// ---------- fp32 -> bf16 bulk convert ----------
__global__ void cvt_f32_to_bf16(const float* __restrict__ src,
                                unsigned short* __restrict__ dst, int n) {
    int i = (blockIdx.x * blockDim.x + threadIdx.x) * 4;
    if (i >= n) return;
    float4 v = *(const float4*)(src + i);
    ushort4 o;
    o.x = f2bf(v.x); o.y = f2bf(v.y); o.z = f2bf(v.z); o.w = f2bf(v.w);
    *(ushort4*)(dst + i) = o;
}

// ---------- transpose + convert: src[R][C] f32 -> dst[C][R] bf16 ----------
__global__ void transpose_cvt(const float* __restrict__ src,
                              unsigned short* __restrict__ dst, int R, int C) {
    __shared__ float tile[32][33];
    int ct = blockIdx.x, rt = blockIdx.y;
    int tx = threadIdx.x, ty = threadIdx.y;
    #pragma unroll
    for (int i = ty; i < 32; i += 8)
        tile[i][tx] = src[(size_t)(rt * 32 + i) * C + ct * 32 + tx];
    __syncthreads();
    #pragma unroll
    for (int i = ty; i < 32; i += 8)
        dst[(size_t)(ct * 32 + i) * R + rt * 32 + tx] = f2bf(tile[tx][i]);
}

// ---------- 256x256 8-wave MFMA GEMM, phase-split + counted vmcnt ---------
// C[M,N] = A[M,K] * BT[N,K]^T.  BK=32, ring-4 LDS K-tiles (128 KiB dynamic),
// prefetch depth 2, vmcnt(4) at tile boundary (never 0 in steady state).
// LDS swizzle (rule 21, both sides): physical chunk pc = lc ^ ((row>>1)&3),
// applied by pre-swizzling the GLOBAL source column during linear gload_lds
// staging and XOR-ing the ds_read offset.  Reads become 2-way (free).
// MODE 0: scatter-epilogue into qcat/kcatf/vf (proj GEMM, N=1536)
// MODE 1: plain f32 store (Wo GEMM)
template<int MODE>
__global__ __launch_bounds__(512, 2) void gemm8(
    const unsigned short* __restrict__ A,
    const unsigned short* __restrict__ BT,
    float* __restrict__ outF,
    unsigned short* __restrict__ qcat,
    unsigned short* __restrict__ kcatf,
    unsigned short* __restrict__ vf,
    int M, int N, int K, int nbx)
{
    extern __shared__ __align__(16) unsigned short lds[];  // 4 * (8192A + 8192B)

    const int tid = threadIdx.x;
    const int lane = tid & 63, w = tid >> 6;      // 8 waves: 2M x 4N
    const int wm = w >> 2, wn = w & 3;
    const int l15 = lane & 15, lg = lane >> 4;

    // bijective XCD swizzle (gridDim.x % 8 == 0)
    const int cpx = gridDim.x >> 3;
    const int swz = (blockIdx.x & 7) * cpx + (blockIdx.x >> 3);
    const int bx = swz % nbx, by = swz / nbx;
    const int row0 = by * 256, col0 = bx * 256;

    // staging geometry: per tile, wave w writes chunks {w, w+8} (512 ushort
    // each) of the linear 256x32 tile.  lane l -> row c*16 + (l>>2),
    // physical in-row chunk (l&3); global col chunk = (l&3)^((l>>3)&3).
    const int srow0 = w * 16 + (lane >> 2);
    const int scol  = ((lane & 3) ^ ((lane >> 3) & 3)) * 8;
    const unsigned short* Ag = A  + (size_t)row0 * K;
    const unsigned short* Bg = BT + (size_t)col0 * K;

    // swizzled ds_read in-row offset (ushorts): phys chunk = lg ^ ((l15>>1)&3)
    const int rdsw = (lg ^ ((l15 >> 1) & 3)) * 8;
    const int aoff = (wm * 128 + l15) * 32 + rdsw;   // + mf*512
    const int boff = (wn * 64  + l15) * 32 + rdsw;   // + nf*512

    const int NT = K >> 5;

    f32x4 acc[8][4] = {};

    // ---- prologue: stage tiles 0 (buf0) and 1 (buf1) ----
    {
        unsigned short* Ar0 = lds;
        unsigned short* Br0 = lds + 8192;
        unsigned short* Ar1 = lds + 16384;
        unsigned short* Br1 = lds + 16384 + 8192;
        gload16(Ag + (size_t)srow0 * K + scol,              Ar0 + w * 512);
        gload16(Ag + (size_t)(srow0 + 128) * K + scol,      Ar0 + w * 512 + 4096);
        gload16(Bg + (size_t)srow0 * K + scol,              Br0 + w * 512);
        gload16(Bg + (size_t)(srow0 + 128) * K + scol,      Br0 + w * 512 + 4096);
        gload16(Ag + (size_t)srow0 * K + 32 + scol,         Ar1 + w * 512);
        gload16(Ag + (size_t)(srow0 + 128) * K + 32 + scol, Ar1 + w * 512 + 4096);
        gload16(Bg + (size_t)srow0 * K + 32 + scol,         Br1 + w * 512);
        gload16(Bg + (size_t)(srow0 + 128) * K + 32 + scol, Br1 + w * 512 + 4096);
    }
    asm volatile("s_waitcnt vmcnt(4)" ::: "memory");   // tile 0 landed
    __builtin_amdgcn_s_barrier();

    for (int t = 0; t < NT; ++t) {
        const unsigned short* Ar = lds + (t & 3) * 16384;
        const unsigned short* Br = Ar + 8192;
        const bool st = (t + 2) < NT;
        unsigned short* Ad = lds + ((t + 2) & 3) * 16384;
        unsigned short* Bd = Ad + 8192;
        const int kk2 = (t + 2) << 5;

        // ---- phase 0: B frags + A frags mf0-3 ; stage A of t+2 ----
        bf16x8 bfr[4], af[4];
        #pragma unroll
        for (int nf = 0; nf < 4; nf++)
            bfr[nf] = __builtin_bit_cast(bf16x8, *(const uint4*)(Br + boff + nf * 512));
        #pragma unroll
        for (int mf = 0; mf < 4; mf++)
            af[mf] = __builtin_bit_cast(bf16x8, *(const uint4*)(Ar + aoff + mf * 512));
        if (st) {
            gload16(Ag + (size_t)srow0 * K + kk2 + scol,         Ad + w * 512);
            gload16(Ag + (size_t)(srow0 + 128) * K + kk2 + scol, Ad + w * 512 + 4096);
        }
        __builtin_amdgcn_s_barrier();
        asm volatile("s_waitcnt lgkmcnt(0)" ::: "memory");
        __builtin_amdgcn_sched_barrier(0);
        __builtin_amdgcn_s_setprio(1);
        #pragma unroll
        for (int mf = 0; mf < 4; mf++)
            #pragma unroll
            for (int nf = 0; nf < 4; nf++)
                acc[mf][nf] = __builtin_amdgcn_mfma_f32_16x16x32_bf16(
                                  af[mf], bfr[nf], acc[mf][nf], 0, 0, 0);
        __builtin_amdgcn_s_setprio(0);
        __builtin_amdgcn_s_barrier();

        // ---- phase 1: A frags mf4-7 ; stage B of t+2 ; boundary vmcnt ----
        bf16x8 af2[4];
        #pragma unroll
        for (int mf = 0; mf < 4; mf++)
            af2[mf] = __builtin_bit_cast(bf16x8, *(const uint4*)(Ar + aoff + (mf + 4) * 512));
        if (st) {
            gload16(Bg + (size_t)srow0 * K + kk2 + scol,         Bd + w * 512);
            gload16(Bg + (size_t)(srow0 + 128) * K + kk2 + scol, Bd + w * 512 + 4096);
        }
        __builtin_amdgcn_s_barrier();
        asm volatile("s_waitcnt lgkmcnt(0)" ::: "memory");
        __builtin_amdgcn_sched_barrier(0);
        __builtin_amdgcn_s_setprio(1);
        #pragma unroll
        for (int mf = 0; mf < 4; mf++)
            #pragma unroll
            for (int nf = 0; nf < 4; nf++)
                acc[mf + 4][nf] = __builtin_amdgcn_mfma_f32_16x16x32_bf16(
                                      af2[mf], bfr[nf], acc[mf + 4][nf], 0, 0, 0);
        __builtin_amdgcn_s_setprio(0);
        if (st) asm volatile("s_waitcnt vmcnt(4)" ::: "memory");  // t+1 landed
        else    asm volatile("s_waitcnt vmcnt(0)" ::: "memory");  // tail drain
        __builtin_amdgcn_s_barrier();
    }

    // ---- epilogue ----
    #pragma unroll
    for (int mf = 0; mf < 8; mf++) {
        #pragma unroll
        for (int nf = 0; nf < 4; nf++) {
            #pragma unroll
            for (int r = 0; r < 4; r++) {
                int row = row0 + wm * 128 + mf * 16 + lg * 4 + r;
                int col = col0 + wn * 64 + nf * 16 + l15;
                float v = acc[mf][nf][r];
                if (MODE == 1) {
                    outF[(size_t)row * N + col] = v;
                } else {
                    int b = row >> 12, t = row & 4095;
                    unsigned short hv = f2bf(v);
                    if (col < 512) {                       // q_sem
                        int h = col >> 5, d = col & 31;
                        qcat[(((size_t)(b*16 + h))*4096 + t)*64 + d] = hv;
                    } else if (col < 1024) {               // q_geo
                        int c2 = col - 512; int h = c2 >> 5, d = c2 & 31;
                        qcat[(((size_t)(b*16 + h))*4096 + t)*64 + 32 + d] = hv;
                    } else if (col < 1152) {               // k_sem
                        int c2 = col - 1024; int g = c2 >> 5, d = c2 & 31;
                        kcatf[(((size_t)(b*4 + g))*4096 + t)*64 + d] = hv;
                    } else if (col < 1280) {               // k_geo
                        int c2 = col - 1152; int g = c2 >> 5, d = c2 & 31;
                        kcatf[(((size_t)(b*4 + g))*4096 + t)*64 + 32 + d] = hv;
                    } else {                               // v
                        int c2 = col - 1280; int g = c2 >> 6, d = c2 & 63;
                        vf[(((size_t)(b*4 + g))*4096 + t)*64 + d] = hv;
                    }
                }
            }
        }
    }
}

// ---------- RoPE rotate (in-place, dims 32..63 of each 64-dim row) ----------
__global__ void rope_rotate(unsigned short* __restrict__ buf, int nrows, int T) {
    int idx = blockIdx.x * 256 + threadIdx.x;
    int row = idx >> 4, i = idx & 15;
    if (row >= nrows) return;
    int t = row % T;
    float inv = exp2f(-(float)i * 0.8304820237218406f);   // 10000^(-i/16)
    float ang = (float)t * inv;
    float s, c;
    sincosf(ang, &s, &c);
    unsigned short* p = buf + (size_t)row * 64;
    float g1 = bf2f(p[32 + i]), g2 = bf2f(p[48 + i]);
    p[32 + i] = f2bf(g1 * c - g2 * s);
    p[48 + i] = f2bf(g2 * c + g1 * s);
}

// ---------- mem-block pooling: full-res KV -> 1072 summarized keys ----------
// kp: [bg][key][64] row-major.  vt: [bg][d][key] TRANSPOSED (for direct B-frags).
__global__ void pool_kv(const unsigned short* __restrict__ kf,
                        const unsigned short* __restrict__ vfull,
                        unsigned short* __restrict__ kp,
                        unsigned short* __restrict__ vt) {
    int key = blockIdx.x % KTOT;
    int bg  = blockIdx.x / KTOT;
    int d = threadIdx.x;
    size_t srcbase = (size_t)bg * T_ * 64;
    size_t kdst = ((size_t)bg * KTOT + key) * 64 + d;
    size_t vdst = ((size_t)bg * 64 + d) * KTOT + key;
    if (key < NBLK) {
        float sk = 0.f, sv = 0.f;
        for (int j = 0; j < MB_; j++) {
            size_t o = srcbase + (size_t)(key * MB_ + j) * 64 + d;
            sk += bf2f(kf[o]);
            sv += bf2f(vfull[o]);
        }
        kp[kdst] = f2bf(sk * (1.f / 64.f));
        vt[vdst] = f2bf(sv * (1.f / 64.f));
    } else {
        int t = REMOTE + key - NBLK;
        size_t o = srcbase + (size_t)t * 64 + d;
        kp[kdst] = kf[o];
        vt[vdst] = vfull[o];
    }
}

// ---------- MFMA flash attention, wave-independent (NO barriers) ----------
__global__ __launch_bounds__(256) void attn_fwd(
    const unsigned short* __restrict__ qcat,
    const unsigned short* __restrict__ kp,   // [bg][key][64]
    const unsigned short* __restrict__ vt,   // [bg][d][KTOT]
    const float* __restrict__ ls,
    unsigned short* __restrict__ attn_out)
{
    __shared__ unsigned short Pl[4][32][72];   // per-wave P tile (bf16)

    const int tid = threadIdx.x;
    const int lane = tid & 63, w = tid >> 6;
    const int l15 = lane & 15, lg = lane >> 4;

    const int wid = blockIdx.x * 4 + w;        // 0..4095
    const int hb = wid & 31;
    const int iu = wid >> 5;                   // schedule slot 0..127
    int i;
    if (iu < 32)       i = 127 - iu;
    else if (iu == 32) i = 0;
    else if (iu == 33) i = 1;
    else               i = iu - 32;
    const int h = hb & 15, b = hb >> 4, g = h >> 2;
    const int q0 = i * 32;

    int ktmax;
    if (q0 < 64) ktmax = NTILES;               // uniform rows: all keys
    else {
        int lastkey = q0 + 31 - 3024;          // max valid local key index
        ktmax = (lastkey < NBLK) ? 1 : (lastkey / 64 + 1);
    }

    const float sc = __expf(ls[h]) * 0.17677669529663687f;   // exp(ls)/sqrt(32)

    bf16x8 aq[2][2];
    const unsigned short* qbase = qcat + (((size_t)(b * 16 + h)) * T_ + q0) * 64;
    #pragma unroll
    for (int rf = 0; rf < 2; rf++)
        #pragma unroll
        for (int kh = 0; kh < 2; kh++)
            aq[rf][kh] = __builtin_bit_cast(bf16x8,
                *(const uint4*)(qbase + (size_t)(rf*16 + l15)*64 + kh*32 + lg*8));

    float m[2][4], lrun[2][4];
    #pragma unroll
    for (int rf = 0; rf < 2; rf++)
        #pragma unroll
        for (int r = 0; r < 4; r++) { m[rf][r] = -1e9f; lrun[rf][r] = 0.f; }
    f32x4 oacc[2][4] = {};

    const unsigned short* kbase = kp + ((size_t)(b * 4 + g)) * KTOT * 64;
    const unsigned short* vbase = vt + ((size_t)(b * 4 + g)) * 64 * KTOT;

    for (int kt = 0; kt < ktmax; kt++) {
        const int kb = kt * 64;

        bf16x8 bk[4][2];
        #pragma unroll
        for (int nf = 0; nf < 4; nf++) {
            int krow = kb + nf*16 + l15;
            int krc = krow < KTOT ? krow : KTOT - 1;     // clamp (masked later)
            #pragma unroll
            for (int kh = 0; kh < 2; kh++)
                bk[nf][kh] = __builtin_bit_cast(bf16x8,
                    *(const uint4*)(kbase + (size_t)krc * 64 + kh*32 + lg*8));
        }

        f32x4 s[2][4] = {};
        #pragma unroll
        for (int rf = 0; rf < 2; rf++)
            #pragma unroll
            for (int nf = 0; nf < 4; nf++)
                #pragma unroll
                for (int kh = 0; kh < 2; kh++)
                    s[rf][nf] = __builtin_amdgcn_mfma_f32_16x16x32_bf16(
                                    aq[rf][kh], bk[nf][kh], s[rf][nf], 0, 0, 0);

        bf16x8 bv[4][2];
        #pragma unroll
        for (int nfv = 0; nfv < 4; nfv++)
            #pragma unroll
            for (int kh = 0; kh < 2; kh++) {
                int kc = kb + kh*32 + lg*8;
                int kcc = (kc + 8 <= KTOT) ? kc : KTOT - 8;  // clamp (P=0 there)
                bv[nfv][kh] = __builtin_bit_cast(bf16x8,
                    *(const uint4*)(vbase + (size_t)(nfv*16 + l15) * KTOT + kcc));
            }

        #pragma unroll
        for (int rf = 0; rf < 2; rf++) {
            #pragma unroll
            for (int r = 0; r < 4; r++) {
                const int qpos = q0 + rf*16 + lg*4 + r;
                float vals[4];
                float tmax = -INFINITY;
                #pragma unroll
                for (int nf = 0; nf < 4; nf++) {
                    int key = kb + nf*16 + l15;
                    float v = s[rf][nf][r] * sc;
                    int kpos = (key < NBLK) ? key * 64 + 63 : 3024 + key;
                    v = (key < KTOT) ? ((kpos <= qpos) ? v : -1e9f) : -INFINITY;
                    vals[nf] = v;
                    tmax = fmaxf(tmax, v);
                }
                #pragma unroll
                for (int d = 1; d < 16; d <<= 1)
                    tmax = fmaxf(tmax, __shfl_xor(tmax, d));
                float mn = fmaxf(m[rf][r], tmax);
                float scl = __expf(m[rf][r] - mn);
                m[rf][r] = mn;
                float rs = 0.f;
                #pragma unroll
                for (int nf = 0; nf < 4; nf++) {
                    unsigned short pb = f2bf(__expf(vals[nf] - mn));
                    rs += bf2f(pb);          // sum the ROUNDED p: exact convex comb
                    Pl[w][rf*16 + lg*4 + r][nf*16 + l15] = pb;
                }
                #pragma unroll
                for (int d = 1; d < 16; d <<= 1)
                    rs += __shfl_xor(rs, d);
                lrun[rf][r] = lrun[rf][r] * scl + rs;
                #pragma unroll
                for (int nfv = 0; nfv < 4; nfv++)
                    oacc[rf][nfv][r] *= scl;
            }
        }

        #pragma unroll
        for (int rf = 0; rf < 2; rf++) {
            bf16x8 pa[2];
            #pragma unroll
            for (int kh = 0; kh < 2; kh++)
                pa[kh] = __builtin_bit_cast(bf16x8,
                    *(const uint4*)&Pl[w][rf*16 + l15][kh*32 + lg*8]);
            #pragma unroll
            for (int nfv = 0; nfv < 4; nfv++)
                #pragma unroll
                for (int kh = 0; kh < 2; kh++)
                    oacc[rf][nfv] = __builtin_amdgcn_mfma_f32_16x16x32_bf16(
                                        pa[kh], bv[nfv][kh], oacc[rf][nfv], 0, 0, 0);
        }
    }

    #pragma unroll
    for (int rf = 0; rf < 2; rf++) {
        #pragma unroll
        for (int r = 0; r < 4; r++) {
            float inv = 1.f / lrun[rf][r];
            int q = q0 + rf*16 + lg*4 + r;
            size_t obase = ((size_t)(b * T_ + q)) * 1024 + h * 64;
            #pragma unroll
            for (int nfv = 0; nfv < 4; nfv++)
                attn_out[obase + nfv*16 + l15] = f2bf(oacc[rf][nfv][r] * inv);
        }
    }
}

// ---------- host launch ----------
extern "C" void kernel_launch(void* const* d_in, const int* in_sizes, int n_in,
                              void* d_out, int out_size, void* d_ws, size_t ws_size,
                              hipStream_t stream) {
    const float* x      = (const float*)d_in[0];
    const float* Wq_sem = (const float*)d_in[1];
    const float* Wk_sem = (const float*)d_in[2];
    const float* Wq_geo = (const float*)d_in[3];
    const float* Wk_geo = (const float*)d_in[4];
    const float* Wv     = (const float*)d_in[5];
    const float* Wo     = (const float*)d_in[6];
    const float* ls     = (const float*)d_in[7];

    char* w = (char*)d_ws;
    auto alloc = [&](size_t bytes) {
        char* p = w;
        w += (bytes + 255) & ~(size_t)255;
        return p;
    };
    unsigned short* xb    = (unsigned short*)alloc((size_t)8192 * 2048 * 2);
    unsigned short* WcatT = (unsigned short*)alloc((size_t)1536 * 2048 * 2);
    unsigned short* WoT   = (unsigned short*)alloc((size_t)2048 * 1024 * 2);
    unsigned short* qcat  = (unsigned short*)alloc((size_t)2 * 16 * 4096 * 64 * 2);
    unsigned short* kcatf = (unsigned short*)alloc((size_t)2 * 4 * 4096 * 64 * 2);
    unsigned short* vfull = (unsigned short*)alloc((size_t)2 * 4 * 4096 * 64 * 2);
    unsigned short* kcatp = (unsigned short*)alloc((size_t)2 * 4 * 1072 * 64 * 2);
    unsigned short* vpool = (unsigned short*)alloc((size_t)2 * 4 * 1072 * 64 * 2);
    unsigned short* aout  = (unsigned short*)alloc((size_t)8192 * 1024 * 2);

    // allow 128 KiB dynamic LDS for the 8-wave GEMMs (idempotent)
    hipFuncSetAttribute(reinterpret_cast<const void*>(&gemm8<0>),
                        hipFuncAttributeMaxDynamicSharedMemorySize, 131072);
    hipFuncSetAttribute(reinterpret_cast<const void*>(&gemm8<1>),
                        hipFuncAttributeMaxDynamicSharedMemorySize, 131072);

    // 1) x -> bf16
    cvt_f32_to_bf16<<<16384, 256, 0, stream>>>(x, xb, 8192 * 2048);

    // 2) weights -> bf16, transposed to [N][K]
    dim3 tb(32, 8);
    transpose_cvt<<<dim3(16, 64), tb, 0, stream>>>(Wq_sem, WcatT + (size_t)0    * 2048, 2048, 512);
    transpose_cvt<<<dim3(16, 64), tb, 0, stream>>>(Wq_geo, WcatT + (size_t)512  * 2048, 2048, 512);
    transpose_cvt<<<dim3( 4, 64), tb, 0, stream>>>(Wk_sem, WcatT + (size_t)1024 * 2048, 2048, 128);
    transpose_cvt<<<dim3( 4, 64), tb, 0, stream>>>(Wk_geo, WcatT + (size_t)1152 * 2048, 2048, 128);
    transpose_cvt<<<dim3( 8, 64), tb, 0, stream>>>(Wv,     WcatT + (size_t)1280 * 2048, 2048, 256);
    transpose_cvt<<<dim3(64, 32), tb, 0, stream>>>(Wo, WoT, 1024, 2048);

    // 3) fused projection GEMM -> qcat / kcatf / vfull (bf16)
    gemm8<0><<<192, 512, 131072, stream>>>(
        xb, WcatT, nullptr, qcat, kcatf, vfull, 8192, 1536, 2048, 6);

    // 4) RoPE on geo halves
    rope_rotate<<<8192, 256, 0, stream>>>(qcat, 2 * 16 * 4096, 4096);
    rope_rotate<<<2048, 256, 0, stream>>>(kcatf, 2 * 4 * 4096, 4096);

    // 5) memory-block pooling (K row-major, V transposed)
    pool_kv<<<8 * KTOT, 64, 0, stream>>>(kcatf, vfull, kcatp, vpool);

    // 6) wave-independent MFMA flash attention
    attn_fwd<<<dim3(1024), 256, 0, stream>>>(qcat, kcatp, vpool, ls, aout);

    // 7) output projection -> d_out (fp32)
    gemm8<1><<<256, 512, 131072, stream>>>(
        aout, WoT, (float*)d_out, nullptr, nullptr, nullptr, 8192, 2048, 1024, 8);
}

// Round 7
// 221.519 us; speedup vs baseline: 3.5058x; 1.0006x over previous
//
#include <hip/hip_runtime.h>
#include <math.h>

// ---------- constants ----------
#define B_  2
#define T_  4096
#define DM  2048
#define H_  16
#define HKV 4
#define DV_ 64
#define MB_ 64
#define LW_ 1024
#define REMOTE 3072     // T - LW
#define NBLK 48         // REMOTE/MB
#define KTOT 1072       // NBLK + LW
#define NTILES 17       // ceil(1072/64)

typedef __bf16 bf16x8 __attribute__((ext_vector_type(8)));
typedef float  f32x4  __attribute__((ext_vector_type(4)));

__device__ __forceinline__ float bf2f(unsigned short u) {
    unsigned int x = ((unsigned int)u) << 16;
    return __builtin_bit_cast(float, x);
}
__device__ __forceinline__ unsigned short f2bf(float f) {
    unsigned int x = __builtin_bit_cast(unsigned int, f);
    x = x + 0x7fffu + ((x >> 16) & 1u);   // round-to-nearest-even
    return (unsigned short)(x >> 16);
}

// async global->LDS, 16B per lane; LDS dest = wave-uniform base + lane*16
__device__ __forceinline__ void gload16(const unsigned short* gsrc,
                                        unsigned short* ldst) {
    __builtin_amdgcn_global_load_lds(
        (const __attribute__((address_space(1))) void*)gsrc,
        (__attribute__((address_space(3))) void*)ldst,
        16, 0, 0);
}

// ---------- fp32 -> bf16 bulk convert ----------
__global__ void cvt_f32_to_bf16(const float* __restrict__ src,
                                unsigned short* __restrict__ dst, int n) {
    int i = (blockIdx.x * blockDim.x + threadIdx.x) * 4;
    if (i >= n) return;
    float4 v = *(const float4*)(src + i);
    ushort4 o;
    o.x = f2bf(v.x); o.y = f2bf(v.y); o.z = f2bf(v.z); o.w = f2bf(v.w);
    *(ushort4*)(dst + i) = o;
}

// ---------- transpose + convert: src[R][C] f32 -> dst[C][R] bf16 ----------
__global__ void transpose_cvt(const float* __restrict__ src,
                              unsigned short* __restrict__ dst, int R, int C) {
    __shared__ float tile[32][33];
    int ct = blockIdx.x, rt = blockIdx.y;
    int tx = threadIdx.x, ty = threadIdx.y;
    #pragma unroll
    for (int i = ty; i < 32; i += 8)
        tile[i][tx] = src[(size_t)(rt * 32 + i) * C + ct * 32 + tx];
    __syncthreads();
    #pragma unroll
    for (int i = ty; i < 32; i += 8)
        dst[(size_t)(ct * 32 + i) * R + rt * 32 + tx] = f2bf(tile[tx][i]);
}

// ---------- 128x128 4-wave MFMA GEMM: ring-3 LDS + counted vmcnt ----------
// C[M,N] = A[M,K] * BT[N,K]^T.  BK=32, ring-3 of 16 KB tile-pairs (48 KB),
// prefetch depth 2, ONE barrier + ONE vmcnt(4) per K-tile (never 0 in
// steady state).  3 blocks/CU -> inter-block overlap fills residual stalls.
// LDS swizzle (both sides): phys chunk = logical ^ ((row>>1)&3), realized by
// pre-swizzling the GLOBAL source column (linear gload_lds dest) and XOR on
// the ds_read offset.  Verified conflict-free (R6: SQ_LDS_BANK_CONFLICT=0).
// MODE 0: scatter-epilogue into qcat/kcatf/vf (proj GEMM, N=1536)
// MODE 1: plain f32 store (Wo GEMM)
template<int MODE>
__global__ __launch_bounds__(256, 3) void gemmP(
    const unsigned short* __restrict__ A,
    const unsigned short* __restrict__ BT,
    float* __restrict__ outF,
    unsigned short* __restrict__ qcat,
    unsigned short* __restrict__ kcatf,
    unsigned short* __restrict__ vf,
    int M, int N, int K, int nbx)
{
    extern __shared__ __align__(16) unsigned short lds[];  // 3*(4096A+4096B)

    const int tid = threadIdx.x;
    const int lane = tid & 63, w = tid >> 6;   // 4 waves: 2x2
    const int wr = w >> 1, wc = w & 1;
    const int l15 = lane & 15, lg = lane >> 4;

    // bijective XCD swizzle (gridDim.x % 8 == 0)
    const int cpx = gridDim.x >> 3;
    const int swz = (blockIdx.x & 7) * cpx + (blockIdx.x >> 3);
    const int bx = swz % nbx, by = swz / nbx;
    const int row0 = by * 128, col0 = bx * 128;

    // staging: 512 chunks(16B)/tile/matrix; thread covers chunks {tid, tid+256}
    // dest chunk i -> row i>>2, phys pos i&3; source logical col chunk =
    // (i&3) ^ ((i>>3)&3)  (the involution the reads also apply)
    const int scol = ((lane & 3) ^ ((lane >> 3) & 3)) * 8;
    const int srA = w * 16 + (lane >> 2);           // + j*64
    const unsigned short* Ag = A  + (size_t)row0 * K;
    const unsigned short* Bg = BT + (size_t)col0 * K;

    // swizzled ds_read in-row chunk: phys = lg ^ ((l15>>1)&3)
    const int rdsw = (lg ^ ((l15 >> 1) & 3)) * 8;
    const int aoff = (wr * 64 + l15) * 32 + rdsw;   // + mf*16*32
    const int boff = (wc * 64 + l15) * 32 + rdsw;   // + nf*16*32

    const int NT = K >> 5;
    f32x4 acc[4][4] = {};

    // stage tile t (K-offset kk) into slot s
    auto stage = [&](int s, int kk) {
        unsigned short* sa = lds + s * 8192;
        unsigned short* sb = sa + 4096;
        #pragma unroll
        for (int j = 0; j < 2; j++) {
            gload16(Ag + (size_t)(srA + j * 64) * K + kk + scol,
                    sa + (j * 256 + w * 64) * 8);
            gload16(Bg + (size_t)(srA + j * 64) * K + kk + scol,
                    sb + (j * 256 + w * 64) * 8);
        }
    };

    // prologue: tiles 0,1 -> slots 0,1 ; wait tile 0
    stage(0, 0);
    stage(1, 32);
    asm volatile("s_waitcnt vmcnt(4)" ::: "memory");

    int rs = 0;                                  // read slot = t % 3
    for (int t = 0; t < NT; ++t) {
        __builtin_amdgcn_s_barrier();            // prev readers of write-slot done
        const bool st = (t + 2) < NT;
        if (st) stage(rs == 0 ? 2 : rs - 1, (t + 2) << 5);   // slot (t+2)%3

        const unsigned short* As_ = lds + rs * 8192;
        const unsigned short* Bs_ = As_ + 4096;
        bf16x8 af[4], bfr[4];
        #pragma unroll
        for (int mf = 0; mf < 4; mf++)
            af[mf] = __builtin_bit_cast(bf16x8, *(const uint4*)&As_[aoff + mf * 512]);
        #pragma unroll
        for (int nf = 0; nf < 4; nf++)
            bfr[nf] = __builtin_bit_cast(bf16x8, *(const uint4*)&Bs_[boff + nf * 512]);

        __builtin_amdgcn_s_setprio(1);
        #pragma unroll
        for (int mf = 0; mf < 4; mf++)
            #pragma unroll
            for (int nf = 0; nf < 4; nf++)
                acc[mf][nf] = __builtin_amdgcn_mfma_f32_16x16x32_bf16(
                                  af[mf], bfr[nf], acc[mf][nf], 0, 0, 0);
        __builtin_amdgcn_s_setprio(0);

        if (st) asm volatile("s_waitcnt vmcnt(4)" ::: "memory");  // t+1 landed
        else    asm volatile("s_waitcnt vmcnt(0)" ::: "memory");  // tail drain
        rs = (rs == 2) ? 0 : rs + 1;
    }

    // ---- epilogue ----
    #pragma unroll
    for (int mf = 0; mf < 4; mf++) {
        #pragma unroll
        for (int nf = 0; nf < 4; nf++) {
            #pragma unroll
            for (int r = 0; r < 4; r++) {
                int row = row0 + wr * 64 + mf * 16 + lg * 4 + r;
                int col = col0 + wc * 64 + nf * 16 + l15;
                float v = acc[mf][nf][r];
                if (MODE == 1) {
                    outF[(size_t)row * N + col] = v;
                } else {
                    int b = row >> 12, t = row & 4095;
                    unsigned short hv = f2bf(v);
                    if (col < 512) {                       // q_sem
                        int h = col >> 5, d = col & 31;
                        qcat[(((size_t)(b*16 + h))*4096 + t)*64 + d] = hv;
                    } else if (col < 1024) {               // q_geo
                        int c2 = col - 512; int h = c2 >> 5, d = c2 & 31;
                        qcat[(((size_t)(b*16 + h))*4096 + t)*64 + 32 + d] = hv;
                    } else if (col < 1152) {               // k_sem
                        int c2 = col - 1024; int g = c2 >> 5, d = c2 & 31;
                        kcatf[(((size_t)(b*4 + g))*4096 + t)*64 + d] = hv;
                    } else if (col < 1280) {               // k_geo
                        int c2 = col - 1152; int g = c2 >> 5, d = c2 & 31;
                        kcatf[(((size_t)(b*4 + g))*4096 + t)*64 + 32 + d] = hv;
                    } else {                               // v
                        int c2 = col - 1280; int g = c2 >> 6, d = c2 & 63;
                        vf[(((size_t)(b*4 + g))*4096 + t)*64 + d] = hv;
                    }
                }
            }
        }
    }
}

// ---------- RoPE rotate (in-place, dims 32..63 of each 64-dim row) ----------
__global__ void rope_rotate(unsigned short* __restrict__ buf, int nrows, int T) {
    int idx = blockIdx.x * 256 + threadIdx.x;
    int row = idx >> 4, i = idx & 15;
    if (row >= nrows) return;
    int t = row % T;
    float inv = exp2f(-(float)i * 0.8304820237218406f);   // 10000^(-i/16)
    float ang = (float)t * inv;
    float s, c;
    sincosf(ang, &s, &c);
    unsigned short* p = buf + (size_t)row * 64;
    float g1 = bf2f(p[32 + i]), g2 = bf2f(p[48 + i]);
    p[32 + i] = f2bf(g1 * c - g2 * s);
    p[48 + i] = f2bf(g2 * c + g1 * s);
}

// ---------- mem-block pooling: full-res KV -> 1072 summarized keys ----------
// kp: [bg][key][64] row-major.  vt: [bg][d][key] TRANSPOSED (for direct B-frags).
__global__ void pool_kv(const unsigned short* __restrict__ kf,
                        const unsigned short* __restrict__ vfull,
                        unsigned short* __restrict__ kp,
                        unsigned short* __restrict__ vt) {
    int key = blockIdx.x % KTOT;
    int bg  = blockIdx.x / KTOT;
    int d = threadIdx.x;
    size_t srcbase = (size_t)bg * T_ * 64;
    size_t kdst = ((size_t)bg * KTOT + key) * 64 + d;
    size_t vdst = ((size_t)bg * 64 + d) * KTOT + key;
    if (key < NBLK) {
        float sk = 0.f, sv = 0.f;
        for (int j = 0; j < MB_; j++) {
            size_t o = srcbase + (size_t)(key * MB_ + j) * 64 + d;
            sk += bf2f(kf[o]);
            sv += bf2f(vfull[o]);
        }
        kp[kdst] = f2bf(sk * (1.f / 64.f));
        vt[vdst] = f2bf(sv * (1.f / 64.f));
    } else {
        int t = REMOTE + key - NBLK;
        size_t o = srcbase + (size_t)t * 64 + d;
        kp[kdst] = kf[o];
        vt[vdst] = vfull[o];
    }
}

// ---------- MFMA flash attention, wave-independent (NO barriers) ----------
__global__ __launch_bounds__(256) void attn_fwd(
    const unsigned short* __restrict__ qcat,
    const unsigned short* __restrict__ kp,   // [bg][key][64]
    const unsigned short* __restrict__ vt,   // [bg][d][KTOT]
    const float* __restrict__ ls,
    unsigned short* __restrict__ attn_out)
{
    __shared__ unsigned short Pl[4][32][72];   // per-wave P tile (bf16)

    const int tid = threadIdx.x;
    const int lane = tid & 63, w = tid >> 6;
    const int l15 = lane & 15, lg = lane >> 4;

    const int wid = blockIdx.x * 4 + w;        // 0..4095
    const int hb = wid & 31;
    const int iu = wid >> 5;                   // schedule slot 0..127
    int i;
    if (iu < 32)       i = 127 - iu;
    else if (iu == 32) i = 0;
    else if (iu == 33) i = 1;
    else               i = iu - 32;
    const int h = hb & 15, b = hb >> 4, g = h >> 2;
    const int q0 = i * 32;

    int ktmax;
    if (q0 < 64) ktmax = NTILES;               // uniform rows: all keys
    else {
        int lastkey = q0 + 31 - 3024;          // max valid local key index
        ktmax = (lastkey < NBLK) ? 1 : (lastkey / 64 + 1);
    }

    const float sc = __expf(ls[h]) * 0.17677669529663687f;   // exp(ls)/sqrt(32)

    bf16x8 aq[2][2];
    const unsigned short* qbase = qcat + (((size_t)(b * 16 + h)) * T_ + q0) * 64;
    #pragma unroll
    for (int rf = 0; rf < 2; rf++)
        #pragma unroll
        for (int kh = 0; kh < 2; kh++)
            aq[rf][kh] = __builtin_bit_cast(bf16x8,
                *(const uint4*)(qbase + (size_t)(rf*16 + l15)*64 + kh*32 + lg*8));

    float m[2][4], lrun[2][4];
    #pragma unroll
    for (int rf = 0; rf < 2; rf++)
        #pragma unroll
        for (int r = 0; r < 4; r++) { m[rf][r] = -1e9f; lrun[rf][r] = 0.f; }
    f32x4 oacc[2][4] = {};

    const unsigned short* kbase = kp + ((size_t)(b * 4 + g)) * KTOT * 64;
    const unsigned short* vbase = vt + ((size_t)(b * 4 + g)) * 64 * KTOT;

    for (int kt = 0; kt < ktmax; kt++) {
        const int kb = kt * 64;

        bf16x8 bk[4][2];
        #pragma unroll
        for (int nf = 0; nf < 4; nf++) {
            int krow = kb + nf*16 + l15;
            int krc = krow < KTOT ? krow : KTOT - 1;     // clamp (masked later)
            #pragma unroll
            for (int kh = 0; kh < 2; kh++)
                bk[nf][kh] = __builtin_bit_cast(bf16x8,
                    *(const uint4*)(kbase + (size_t)krc * 64 + kh*32 + lg*8));
        }

        f32x4 s[2][4] = {};
        #pragma unroll
        for (int rf = 0; rf < 2; rf++)
            #pragma unroll
            for (int nf = 0; nf < 4; nf++)
                #pragma unroll
                for (int kh = 0; kh < 2; kh++)
                    s[rf][nf] = __builtin_amdgcn_mfma_f32_16x16x32_bf16(
                                    aq[rf][kh], bk[nf][kh], s[rf][nf], 0, 0, 0);

        bf16x8 bv[4][2];
        #pragma unroll
        for (int nfv = 0; nfv < 4; nfv++)
            #pragma unroll
            for (int kh = 0; kh < 2; kh++) {
                int kc = kb + kh*32 + lg*8;
                int kcc = (kc + 8 <= KTOT) ? kc : KTOT - 8;  // clamp (P=0 there)
                bv[nfv][kh] = __builtin_bit_cast(bf16x8,
                    *(const uint4*)(vbase + (size_t)(nfv*16 + l15) * KTOT + kcc));
            }

        #pragma unroll
        for (int rf = 0; rf < 2; rf++) {
            #pragma unroll
            for (int r = 0; r < 4; r++) {
                const int qpos = q0 + rf*16 + lg*4 + r;
                float vals[4];
                float tmax = -INFINITY;
                #pragma unroll
                for (int nf = 0; nf < 4; nf++) {
                    int key = kb + nf*16 + l15;
                    float v = s[rf][nf][r] * sc;
                    int kpos = (key < NBLK) ? key * 64 + 63 : 3024 + key;
                    v = (key < KTOT) ? ((kpos <= qpos) ? v : -1e9f) : -INFINITY;
                    vals[nf] = v;
                    tmax = fmaxf(tmax, v);
                }
                #pragma unroll
                for (int d = 1; d < 16; d <<= 1)
                    tmax = fmaxf(tmax, __shfl_xor(tmax, d));
                float mn = fmaxf(m[rf][r], tmax);
                float scl = __expf(m[rf][r] - mn);
                m[rf][r] = mn;
                float rs = 0.f;
                #pragma unroll
                for (int nf = 0; nf < 4; nf++) {
                    unsigned short pb = f2bf(__expf(vals[nf] - mn));
                    rs += bf2f(pb);          // sum the ROUNDED p: exact convex comb
                    Pl[w][rf*16 + lg*4 + r][nf*16 + l15] = pb;
                }
                #pragma unroll
                for (int d = 1; d < 16; d <<= 1)
                    rs += __shfl_xor(rs, d);
                lrun[rf][r] = lrun[rf][r] * scl + rs;
                #pragma unroll
                for (int nfv = 0; nfv < 4; nfv++)
                    oacc[rf][nfv][r] *= scl;
            }
        }

        #pragma unroll
        for (int rf = 0; rf < 2; rf++) {
            bf16x8 pa[2];
            #pragma unroll
            for (int kh = 0; kh < 2; kh++)
                pa[kh] = __builtin_bit_cast(bf16x8,
                    *(const uint4*)&Pl[w][rf*16 + l15][kh*32 + lg*8]);
            #pragma unroll
            for (int nfv = 0; nfv < 4; nfv++)
                #pragma unroll
                for (int kh = 0; kh < 2; kh++)
                    oacc[rf][nfv] = __builtin_amdgcn_mfma_f32_16x16x32_bf16(
                                        pa[kh], bv[nfv][kh], oacc[rf][nfv], 0, 0, 0);
        }
    }

    #pragma unroll
    for (int rf = 0; rf < 2; rf++) {
        #pragma unroll
        for (int r = 0; r < 4; r++) {
            float inv = 1.f / lrun[rf][r];
            int q = q0 + rf*16 + lg*4 + r;
            size_t obase = ((size_t)(b * T_ + q)) * 1024 + h * 64;
            #pragma unroll
            for (int nfv = 0; nfv < 4; nfv++)
                attn_out[obase + nfv*16 + l15] = f2bf(oacc[rf][nfv][r] * inv);
        }
    }
}

// ---------- host launch ----------
extern "C" void kernel_launch(void* const* d_in, const int* in_sizes, int n_in,
                              void* d_out, int out_size, void* d_ws, size_t ws_size,
                              hipStream_t stream) {
    const float* x      = (const float*)d_in[0];
    const float* Wq_sem = (const float*)d_in[1];
    const float* Wk_sem = (const float*)d_in[2];
    const float* Wq_geo = (const float*)d_in[3];
    const float* Wk_geo = (const float*)d_in[4];
    const float* Wv     = (const float*)d_in[5];
    const float* Wo     = (const float*)d_in[6];
    const float* ls     = (const float*)d_in[7];

    char* w = (char*)d_ws;
    auto alloc = [&](size_t bytes) {
        char* p = w;
        w += (bytes + 255) & ~(size_t)255;
        return p;
    };
    unsigned short* xb    = (unsigned short*)alloc((size_t)8192 * 2048 * 2);
    unsigned short* WcatT = (unsigned short*)alloc((size_t)1536 * 2048 * 2);
    unsigned short* WoT   = (unsigned short*)alloc((size_t)2048 * 1024 * 2);
    unsigned short* qcat  = (unsigned short*)alloc((size_t)2 * 16 * 4096 * 64 * 2);
    unsigned short* kcatf = (unsigned short*)alloc((size_t)2 * 4 * 4096 * 64 * 2);
    unsigned short* vfull = (unsigned short*)alloc((size_t)2 * 4 * 4096 * 64 * 2);
    unsigned short* kcatp = (unsigned short*)alloc((size_t)2 * 4 * 1072 * 64 * 2);
    unsigned short* vpool = (unsigned short*)alloc((size_t)2 * 4 * 1072 * 64 * 2);
    unsigned short* aout  = (unsigned short*)alloc((size_t)8192 * 1024 * 2);

    // allow 48 KiB dynamic LDS (idempotent)
    hipFuncSetAttribute(reinterpret_cast<const void*>(&gemmP<0>),
                        hipFuncAttributeMaxDynamicSharedMemorySize, 49152);
    hipFuncSetAttribute(reinterpret_cast<const void*>(&gemmP<1>),
                        hipFuncAttributeMaxDynamicSharedMemorySize, 49152);

    // 1) x -> bf16
    cvt_f32_to_bf16<<<16384, 256, 0, stream>>>(x, xb, 8192 * 2048);

    // 2) weights -> bf16, transposed to [N][K]
    dim3 tb(32, 8);
    transpose_cvt<<<dim3(16, 64), tb, 0, stream>>>(Wq_sem, WcatT + (size_t)0    * 2048, 2048, 512);
    transpose_cvt<<<dim3(16, 64), tb, 0, stream>>>(Wq_geo, WcatT + (size_t)512  * 2048, 2048, 512);
    transpose_cvt<<<dim3( 4, 64), tb, 0, stream>>>(Wk_sem, WcatT + (size_t)1024 * 2048, 2048, 128);
    transpose_cvt<<<dim3( 4, 64), tb, 0, stream>>>(Wk_geo, WcatT + (size_t)1152 * 2048, 2048, 128);
    transpose_cvt<<<dim3( 8, 64), tb, 0, stream>>>(Wv,     WcatT + (size_t)1280 * 2048, 2048, 256);
    transpose_cvt<<<dim3(64, 32), tb, 0, stream>>>(Wo, WoT, 1024, 2048);

    // 3) fused projection GEMM -> qcat / kcatf / vfull (bf16)
    gemmP<0><<<768, 256, 49152, stream>>>(
        xb, WcatT, nullptr, qcat, kcatf, vfull, 8192, 1536, 2048, 12);

    // 4) RoPE on geo halves
    rope_rotate<<<8192, 256, 0, stream>>>(qcat, 2 * 16 * 4096, 4096);
    rope_rotate<<<2048, 256, 0, stream>>>(kcatf, 2 * 4 * 4096, 4096);

    // 5) memory-block pooling (K row-major, V transposed)
    pool_kv<<<8 * KTOT, 64, 0, stream>>>(kcatf, vfull, kcatp, vpool);

    // 6) wave-independent MFMA flash attention
    attn_fwd<<<dim3(1024), 256, 0, stream>>>(qcat, kcatp, vpool, ls, aout);

    // 7) output projection -> d_out (fp32)
    gemmP<1><<<1024, 256, 49152, stream>>>(
        aout, WoT, (float*)d_out, nullptr, nullptr, nullptr, 8192, 2048, 1024, 16);
}

// Round 8
// 203.401 us; speedup vs baseline: 3.8181x; 1.0891x over previous
//
#include <hip/hip_runtime.h>
#include <math.h>

// ---------- constants ----------
#define B_  2
#define T_  4096
#define DM  2048
#define H_  16
#define HKV 4
#define DV_ 64
#define MB_ 64
#define LW_ 1024
#define REMOTE 3072     // T - LW
#define NBLK 48         // REMOTE/MB
#define KTOT 1072       // NBLK + LW
#define NTILES 17       // ceil(1072/64)

typedef __bf16 bf16x8 __attribute__((ext_vector_type(8)));
typedef float  f32x4  __attribute__((ext_vector_type(4)));

__device__ __forceinline__ float bf2f(unsigned short u) {
    unsigned int x = ((unsigned int)u) << 16;
    return __builtin_bit_cast(float, x);
}
__device__ __forceinline__ unsigned short f2bf(float f) {
    unsigned int x = __builtin_bit_cast(unsigned int, f);
    x = x + 0x7fffu + ((x >> 16) & 1u);   // round-to-nearest-even
    return (unsigned short)(x >> 16);
}

// async global->LDS, 16B per lane; LDS dest = wave-uniform base + lane*16
__device__ __forceinline__ void gload16(const unsigned short* gsrc,
                                        unsigned short* ldst) {
    __builtin_amdgcn_global_load_lds(
        (const __attribute__((address_space(1))) void*)gsrc,
        (__attribute__((address_space(3))) void*)ldst,
        16, 0, 0);
}

// ---------- fp32 -> bf16 bulk convert ----------
__global__ void cvt_f32_to_bf16(const float* __restrict__ src,
                                unsigned short* __restrict__ dst, int n) {
    int i = (blockIdx.x * blockDim.x + threadIdx.x) * 4;
    if (i >= n) return;
    float4 v = *(const float4*)(src + i);
    ushort4 o;
    o.x = f2bf(v.x); o.y = f2bf(v.y); o.z = f2bf(v.z); o.w = f2bf(v.w);
    *(ushort4*)(dst + i) = o;
}

// ---------- transpose + convert: src[R][C] f32 -> dst[C][R] bf16 ----------
__global__ void transpose_cvt(const float* __restrict__ src,
                              unsigned short* __restrict__ dst, int R, int C) {
    __shared__ float tile[32][33];
    int ct = blockIdx.x, rt = blockIdx.y;
    int tx = threadIdx.x, ty = threadIdx.y;
    #pragma unroll
    for (int i = ty; i < 32; i += 8)
        tile[i][tx] = src[(size_t)(rt * 32 + i) * C + ct * 32 + tx];
    __syncthreads();
    #pragma unroll
    for (int i = ty; i < 32; i += 8)
        dst[(size_t)(ct * 32 + i) * R + rt * 32 + tx] = f2bf(tile[tx][i]);
}

// ---------- 128x128 4-wave MFMA GEMM: ring-3 LDS + counted vmcnt ----------
// C[M,N] = A[M,K] * BT[N,K]^T.  BK=32, ring-3 (48 KB), prefetch depth 2,
// ONE barrier + ONE vmcnt(4) per K-tile.  3 blocks/CU.
// LDS swizzle both-sides (verified conflict-free, R6/R7: BANK_CONFLICT=0).
// MODE 0 (proj): fused epilogue — RoPE on geo cols, KV mem-block pooling
//   (remote rows) straight into kp/vt, local rows full-res, q into qcat.
// MODE 1: plain f32 store (Wo GEMM)
template<int MODE>
__global__ __launch_bounds__(256, 3) void gemmP(
    const unsigned short* __restrict__ A,
    const unsigned short* __restrict__ BT,
    float* __restrict__ outF,
    unsigned short* __restrict__ qcat,
    unsigned short* __restrict__ kp,    // [bg][key][64]
    unsigned short* __restrict__ vt,    // [bg][d][KTOT]
    int M, int N, int K, int nbx)
{
    extern __shared__ __align__(16) unsigned short lds[];  // 3*(4096A+4096B)

    const int tid = threadIdx.x;
    const int lane = tid & 63, w = tid >> 6;   // 4 waves: 2x2
    const int wr = w >> 1, wc = w & 1;
    const int l15 = lane & 15, lg = lane >> 4;

    // bijective XCD swizzle (gridDim.x % 8 == 0)
    const int cpx = gridDim.x >> 3;
    const int swz = (blockIdx.x & 7) * cpx + (blockIdx.x >> 3);
    const int bx = swz % nbx, by = swz / nbx;
    const int row0 = by * 128, col0 = bx * 128;

    const int scol = ((lane & 3) ^ ((lane >> 3) & 3)) * 8;
    const int srA = w * 16 + (lane >> 2);           // + j*64
    const unsigned short* Ag = A  + (size_t)row0 * K;
    const unsigned short* Bg = BT + (size_t)col0 * K;

    const int rdsw = (lg ^ ((l15 >> 1) & 3)) * 8;
    const int aoff = (wr * 64 + l15) * 32 + rdsw;   // + mf*512
    const int boff = (wc * 64 + l15) * 32 + rdsw;   // + nf*512

    const int NT = K >> 5;
    f32x4 acc[4][4] = {};

    auto stage = [&](int s, int kk) {
        unsigned short* sa = lds + s * 8192;
        unsigned short* sb = sa + 4096;
        #pragma unroll
        for (int j = 0; j < 2; j++) {
            gload16(Ag + (size_t)(srA + j * 64) * K + kk + scol,
                    sa + (j * 256 + w * 64) * 8);
            gload16(Bg + (size_t)(srA + j * 64) * K + kk + scol,
                    sb + (j * 256 + w * 64) * 8);
        }
    };

    stage(0, 0);
    stage(1, 32);
    asm volatile("s_waitcnt vmcnt(4)" ::: "memory");

    int rs = 0;
    for (int t = 0; t < NT; ++t) {
        __builtin_amdgcn_s_barrier();
        const bool st = (t + 2) < NT;
        if (st) stage(rs == 0 ? 2 : rs - 1, (t + 2) << 5);

        const unsigned short* As_ = lds + rs * 8192;
        const unsigned short* Bs_ = As_ + 4096;
        bf16x8 af[4], bfr[4];
        #pragma unroll
        for (int mf = 0; mf < 4; mf++)
            af[mf] = __builtin_bit_cast(bf16x8, *(const uint4*)&As_[aoff + mf * 512]);
        #pragma unroll
        for (int nf = 0; nf < 4; nf++)
            bfr[nf] = __builtin_bit_cast(bf16x8, *(const uint4*)&Bs_[boff + nf * 512]);

        __builtin_amdgcn_s_setprio(1);
        #pragma unroll
        for (int mf = 0; mf < 4; mf++)
            #pragma unroll
            for (int nf = 0; nf < 4; nf++)
                acc[mf][nf] = __builtin_amdgcn_mfma_f32_16x16x32_bf16(
                                  af[mf], bfr[nf], acc[mf][nf], 0, 0, 0);
        __builtin_amdgcn_s_setprio(0);

        if (st) asm volatile("s_waitcnt vmcnt(4)" ::: "memory");
        else    asm volatile("s_waitcnt vmcnt(0)" ::: "memory");
        rs = (rs == 2) ? 0 : rs + 1;
    }

    // ---- epilogue ----
    if (MODE == 1) {
        #pragma unroll
        for (int mf = 0; mf < 4; mf++)
            #pragma unroll
            for (int nf = 0; nf < 4; nf++)
                #pragma unroll
                for (int r = 0; r < 4; r++) {
                    int row = row0 + wr * 64 + mf * 16 + lg * 4 + r;
                    int col = col0 + wc * 64 + nf * 16 + l15;
                    outF[(size_t)row * N + col] = acc[mf][nf][r];
                }
    } else {
        const int cspan = col0 + wc * 64;       // wave col base (64-aligned)
        const int tbase = row0 & 4095;          // t of tile row 0 (b uniform)
        const int bq = row0 >> 12;

        // RoPE on geo spans: pair (d, d+16) == (nf, nf+1) in-fragment
        if ((cspan >= 512 && cspan < 1024) || (cspan >= 1152 && cspan < 1280)) {
            const float invf = exp2f(-(float)l15 * 0.8304820237218406f);
            #pragma unroll
            for (int mf = 0; mf < 4; mf++) {
                #pragma unroll
                for (int r = 0; r < 4; r++) {
                    float s, c;
                    sincosf((float)(tbase + wr*64 + mf*16 + lg*4 + r) * invf, &s, &c);
                    float a0 = acc[mf][0][r], a1 = acc[mf][1][r];
                    acc[mf][0][r] = a0 * c - a1 * s;
                    acc[mf][1][r] = a1 * c + a0 * s;
                    float a2 = acc[mf][2][r], a3 = acc[mf][3][r];
                    acc[mf][2][r] = a2 * c - a3 * s;
                    acc[mf][3][r] = a3 * c + a2 * s;
                }
            }
        }

        if (cspan < 1024) {
            // ---- Q -> qcat [b][h][t][64] ----
            #pragma unroll
            for (int nf = 0; nf < 4; nf++) {
                int col = cspan + nf * 16 + l15;
                int h = (col < 512) ? (col >> 5) : ((col - 512) >> 5);
                int d = (col < 512) ? (col & 31) : (32 + (col & 31));
                unsigned short* qb =
                    qcat + (((size_t)(bq * 16 + h)) * 4096 + tbase) * 64 + d;
                #pragma unroll
                for (int mf = 0; mf < 4; mf++)
                    #pragma unroll
                    for (int r = 0; r < 4; r++)
                        qb[(size_t)(wr*64 + mf*16 + lg*4 + r) * 64] =
                            f2bf(acc[mf][nf][r]);
            }
        } else if (tbase >= REMOTE) {
            // ---- local K/V rows -> full-res keys 48..1071 ----
            #pragma unroll
            for (int nf = 0; nf < 4; nf++) {
                int col = cspan + nf * 16 + l15;
                #pragma unroll
                for (int mf = 0; mf < 4; mf++)
                    #pragma unroll
                    for (int r = 0; r < 4; r++) {
                        int key = tbase + wr*64 + mf*16 + lg*4 + r - 3024;
                        unsigned short hv = f2bf(acc[mf][nf][r]);
                        if (col < 1280) {
                            int g, dk;
                            if (col < 1152) { g = (col - 1024) >> 5; dk = col & 31; }
                            else            { g = (col - 1152) >> 5; dk = 32 + (col & 31); }
                            kp[(((size_t)(bq*4 + g)) * KTOT + key) * 64 + dk] = hv;
                        } else {
                            int g = (col - 1280) >> 6, dv = col & 63;
                            vt[(((size_t)(bq*4 + g)) * 64 + dv) * KTOT + key] = hv;
                        }
                    }
            }
        } else {
            // ---- remote K/V rows -> mem-block pooled (wr half = one block) ----
            #pragma unroll
            for (int nf = 0; nf < 4; nf++) {
                float ps = 0.f;
                #pragma unroll
                for (int mf = 0; mf < 4; mf++)
                    #pragma unroll
                    for (int r = 0; r < 4; r++) ps += acc[mf][nf][r];
                ps += __shfl_xor(ps, 16);
                ps += __shfl_xor(ps, 32);
                if (lane < 16) {
                    int col = cspan + nf * 16 + l15;
                    int key = (tbase >> 6) + wr;
                    unsigned short hv = f2bf(ps * (1.f / 64.f));
                    if (col < 1280) {
                        int g, dk;
                        if (col < 1152) { g = (col - 1024) >> 5; dk = col & 31; }
                        else            { g = (col - 1152) >> 5; dk = 32 + (col & 31); }
                        kp[(((size_t)(bq*4 + g)) * KTOT + key) * 64 + dk] = hv;
                    } else {
                        int g = (col - 1280) >> 6, dv = col & 63;
                        vt[(((size_t)(bq*4 + g)) * 64 + dv) * KTOT + key] = hv;
                    }
                }
            }
        }
    }
}

// ---------- MFMA flash attention, wave-independent (NO barriers) ----------
__global__ __launch_bounds__(256) void attn_fwd(
    const unsigned short* __restrict__ qcat,
    const unsigned short* __restrict__ kp,   // [bg][key][64]
    const unsigned short* __restrict__ vt,   // [bg][d][KTOT]
    const float* __restrict__ ls,
    unsigned short* __restrict__ attn_out)
{
    __shared__ unsigned short Pl[4][32][72];   // per-wave P tile (bf16)

    const int tid = threadIdx.x;
    const int lane = tid & 63, w = tid >> 6;
    const int l15 = lane & 15, lg = lane >> 4;

    const int wid = blockIdx.x * 4 + w;        // 0..4095
    const int hb = wid & 31;
    const int iu = wid >> 5;                   // schedule slot 0..127
    int i;
    if (iu < 32)       i = 127 - iu;
    else if (iu == 32) i = 0;
    else if (iu == 33) i = 1;
    else               i = iu - 32;
    const int h = hb & 15, b = hb >> 4, g = h >> 2;
    const int q0 = i * 32;

    int ktmax;
    if (q0 < 64) ktmax = NTILES;               // uniform rows: all keys
    else {
        int lastkey = q0 + 31 - 3024;          // max valid local key index
        ktmax = (lastkey < NBLK) ? 1 : (lastkey / 64 + 1);
    }

    const float sc = __expf(ls[h]) * 0.17677669529663687f;   // exp(ls)/sqrt(32)

    bf16x8 aq[2][2];
    const unsigned short* qbase = qcat + (((size_t)(b * 16 + h)) * T_ + q0) * 64;
    #pragma unroll
    for (int rf = 0; rf < 2; rf++)
        #pragma unroll
        for (int kh = 0; kh < 2; kh++)
            aq[rf][kh] = __builtin_bit_cast(bf16x8,
                *(const uint4*)(qbase + (size_t)(rf*16 + l15)*64 + kh*32 + lg*8));

    float m[2][4], lrun[2][4];
    #pragma unroll
    for (int rf = 0; rf < 2; rf++)
        #pragma unroll
        for (int r = 0; r < 4; r++) { m[rf][r] = -1e9f; lrun[rf][r] = 0.f; }
    f32x4 oacc[2][4] = {};

    const unsigned short* kbase = kp + ((size_t)(b * 4 + g)) * KTOT * 64;
    const unsigned short* vbase = vt + ((size_t)(b * 4 + g)) * 64 * KTOT;

    for (int kt = 0; kt < ktmax; kt++) {
        const int kb = kt * 64;

        bf16x8 bk[4][2];
        #pragma unroll
        for (int nf = 0; nf < 4; nf++) {
            int krow = kb + nf*16 + l15;
            int krc = krow < KTOT ? krow : KTOT - 1;     // clamp (masked later)
            #pragma unroll
            for (int kh = 0; kh < 2; kh++)
                bk[nf][kh] = __builtin_bit_cast(bf16x8,
                    *(const uint4*)(kbase + (size_t)krc * 64 + kh*32 + lg*8));
        }

        f32x4 s[2][4] = {};
        #pragma unroll
        for (int rf = 0; rf < 2; rf++)
            #pragma unroll
            for (int nf = 0; nf < 4; nf++)
                #pragma unroll
                for (int kh = 0; kh < 2; kh++)
                    s[rf][nf] = __builtin_amdgcn_mfma_f32_16x16x32_bf16(
                                    aq[rf][kh], bk[nf][kh], s[rf][nf], 0, 0, 0);

        bf16x8 bv[4][2];
        #pragma unroll
        for (int nfv = 0; nfv < 4; nfv++)
            #pragma unroll
            for (int kh = 0; kh < 2; kh++) {
                int kc = kb + kh*32 + lg*8;
                int kcc = (kc + 8 <= KTOT) ? kc : KTOT - 8;  // clamp (P=0 there)
                bv[nfv][kh] = __builtin_bit_cast(bf16x8,
                    *(const uint4*)(vbase + (size_t)(nfv*16 + l15) * KTOT + kcc));
            }

        #pragma unroll
        for (int rf = 0; rf < 2; rf++) {
            #pragma unroll
            for (int r = 0; r < 4; r++) {
                const int qpos = q0 + rf*16 + lg*4 + r;
                float vals[4];
                float tmax = -INFINITY;
                #pragma unroll
                for (int nf = 0; nf < 4; nf++) {
                    int key = kb + nf*16 + l15;
                    float v = s[rf][nf][r] * sc;
                    int kpos = (key < NBLK) ? key * 64 + 63 : 3024 + key;
                    v = (key < KTOT) ? ((kpos <= qpos) ? v : -1e9f) : -INFINITY;
                    vals[nf] = v;
                    tmax = fmaxf(tmax, v);
                }
                #pragma unroll
                for (int d = 1; d < 16; d <<= 1)
                    tmax = fmaxf(tmax, __shfl_xor(tmax, d));
                float mn = fmaxf(m[rf][r], tmax);
                float scl = __expf(m[rf][r] - mn);
                m[rf][r] = mn;
                float rs = 0.f;
                #pragma unroll
                for (int nf = 0; nf < 4; nf++) {
                    unsigned short pb = f2bf(__expf(vals[nf] - mn));
                    rs += bf2f(pb);          // sum the ROUNDED p: exact convex comb
                    Pl[w][rf*16 + lg*4 + r][nf*16 + l15] = pb;
                }
                #pragma unroll
                for (int d = 1; d < 16; d <<= 1)
                    rs += __shfl_xor(rs, d);
                lrun[rf][r] = lrun[rf][r] * scl + rs;
                #pragma unroll
                for (int nfv = 0; nfv < 4; nfv++)
                    oacc[rf][nfv][r] *= scl;
            }
        }

        #pragma unroll
        for (int rf = 0; rf < 2; rf++) {
            bf16x8 pa[2];
            #pragma unroll
            for (int kh = 0; kh < 2; kh++)
                pa[kh] = __builtin_bit_cast(bf16x8,
                    *(const uint4*)&Pl[w][rf*16 + l15][kh*32 + lg*8]);
            #pragma unroll
            for (int nfv = 0; nfv < 4; nfv++)
                #pragma unroll
                for (int kh = 0; kh < 2; kh++)
                    oacc[rf][nfv] = __builtin_amdgcn_mfma_f32_16x16x32_bf16(
                                        pa[kh], bv[nfv][kh], oacc[rf][nfv], 0, 0, 0);
        }
    }

    #pragma unroll
    for (int rf = 0; rf < 2; rf++) {
        #pragma unroll
        for (int r = 0; r < 4; r++) {
            float inv = 1.f / lrun[rf][r];
            int q = q0 + rf*16 + lg*4 + r;
            size_t obase = ((size_t)(b * T_ + q)) * 1024 + h * 64;
            #pragma unroll
            for (int nfv = 0; nfv < 4; nfv++)
                attn_out[obase + nfv*16 + l15] = f2bf(oacc[rf][nfv][r] * inv);
        }
    }
}

// ---------- host launch ----------
extern "C" void kernel_launch(void* const* d_in, const int* in_sizes, int n_in,
                              void* d_out, int out_size, void* d_ws, size_t ws_size,
                              hipStream_t stream) {
    const float* x      = (const float*)d_in[0];
    const float* Wq_sem = (const float*)d_in[1];
    const float* Wk_sem = (const float*)d_in[2];
    const float* Wq_geo = (const float*)d_in[3];
    const float* Wk_geo = (const float*)d_in[4];
    const float* Wv     = (const float*)d_in[5];
    const float* Wo     = (const float*)d_in[6];
    const float* ls     = (const float*)d_in[7];

    char* w = (char*)d_ws;
    auto alloc = [&](size_t bytes) {
        char* p = w;
        w += (bytes + 255) & ~(size_t)255;
        return p;
    };
    unsigned short* xb    = (unsigned short*)alloc((size_t)8192 * 2048 * 2);
    unsigned short* WcatT = (unsigned short*)alloc((size_t)1536 * 2048 * 2);
    unsigned short* WoT   = (unsigned short*)alloc((size_t)2048 * 1024 * 2);
    unsigned short* qcat  = (unsigned short*)alloc((size_t)2 * 16 * 4096 * 64 * 2);
    unsigned short* kp    = (unsigned short*)alloc((size_t)2 * 4 * 1072 * 64 * 2);
    unsigned short* vt    = (unsigned short*)alloc((size_t)2 * 4 * 1072 * 64 * 2);
    unsigned short* aout  = (unsigned short*)alloc((size_t)8192 * 1024 * 2);

    // allow 48 KiB dynamic LDS (idempotent)
    hipFuncSetAttribute(reinterpret_cast<const void*>(&gemmP<0>),
                        hipFuncAttributeMaxDynamicSharedMemorySize, 49152);
    hipFuncSetAttribute(reinterpret_cast<const void*>(&gemmP<1>),
                        hipFuncAttributeMaxDynamicSharedMemorySize, 49152);

    // 1) x -> bf16
    cvt_f32_to_bf16<<<16384, 256, 0, stream>>>(x, xb, 8192 * 2048);

    // 2) weights -> bf16, transposed to [N][K]
    dim3 tb(32, 8);
    transpose_cvt<<<dim3(16, 64), tb, 0, stream>>>(Wq_sem, WcatT + (size_t)0    * 2048, 2048, 512);
    transpose_cvt<<<dim3(16, 64), tb, 0, stream>>>(Wq_geo, WcatT + (size_t)512  * 2048, 2048, 512);
    transpose_cvt<<<dim3( 4, 64), tb, 0, stream>>>(Wk_sem, WcatT + (size_t)1024 * 2048, 2048, 128);
    transpose_cvt<<<dim3( 4, 64), tb, 0, stream>>>(Wk_geo, WcatT + (size_t)1152 * 2048, 2048, 128);
    transpose_cvt<<<dim3( 8, 64), tb, 0, stream>>>(Wv,     WcatT + (size_t)1280 * 2048, 2048, 256);
    transpose_cvt<<<dim3(64, 32), tb, 0, stream>>>(Wo, WoT, 1024, 2048);

    // 3) fused projection GEMM (+RoPE +pooling) -> qcat / kp / vt
    gemmP<0><<<768, 256, 49152, stream>>>(
        xb, WcatT, nullptr, qcat, kp, vt, 8192, 1536, 2048, 12);

    // 4) wave-independent MFMA flash attention
    attn_fwd<<<dim3(1024), 256, 0, stream>>>(qcat, kp, vt, ls, aout);

    // 5) output projection -> d_out (fp32)
    gemmP<1><<<1024, 256, 49152, stream>>>(
        aout, WoT, (float*)d_out, nullptr, nullptr, nullptr, 8192, 2048, 1024, 16);
}